// Round 5
// baseline (463.318 us; speedup 1.0000x reference)
//
#include <hip/hip_runtime.h>
#include <stdint.h>
#include <math.h>

#define JAX_PARTITIONABLE 1

#define NB 8
#define NM 144
#define NM16 16
#define NPTS 500

// ---------------- Threefry-2x32 (JAX-exact) ----------------
__host__ __device__ __forceinline__ uint32_t rotl32(uint32_t x, int r) {
    return (x << r) | (x >> (32 - r));
}

__host__ __device__ inline void threefry2x32(uint32_t k0, uint32_t k1,
                                             uint32_t x0, uint32_t x1,
                                             uint32_t& o0, uint32_t& o1) {
    uint32_t ks2 = k0 ^ k1 ^ 0x1BD11BDAu;
    x0 += k0; x1 += k1;
    const int RA[4] = {13, 15, 26, 6};
    const int RB[4] = {17, 29, 16, 24};
#define R4(ROT) { x0 += x1; x1 = rotl32(x1, ROT[0]); x1 ^= x0; \
                  x0 += x1; x1 = rotl32(x1, ROT[1]); x1 ^= x0; \
                  x0 += x1; x1 = rotl32(x1, ROT[2]); x1 ^= x0; \
                  x0 += x1; x1 = rotl32(x1, ROT[3]); x1 ^= x0; }
    R4(RA); x0 += k1;  x1 += ks2 + 1u;
    R4(RB); x0 += ks2; x1 += k0 + 2u;
    R4(RA); x0 += k0;  x1 += k1 + 3u;
    R4(RB); x0 += k1;  x1 += ks2 + 4u;
    R4(RA); x0 += ks2; x1 += k0 + 5u;
#undef R4
    o0 = x0; o1 = x1;
}

// XLA f32 erf_inv (Giles polynomial pair)
__device__ __forceinline__ float erfinv32(float x) {
    float w = -log1pf(-x * x);
    float p;
    if (w < 5.0f) {
        w = w - 2.5f;
        p = 2.81022636e-08f;
        p = fmaf(p, w, 3.43273939e-07f);
        p = fmaf(p, w, -3.5233877e-06f);
        p = fmaf(p, w, -4.39150654e-06f);
        p = fmaf(p, w, 0.00021858087f);
        p = fmaf(p, w, -0.00125372503f);
        p = fmaf(p, w, -0.00417768164f);
        p = fmaf(p, w, 0.246640727f);
        p = fmaf(p, w, 1.50140941f);
    } else {
        w = sqrtf(w) - 3.0f;
        p = -0.000200214257f;
        p = fmaf(p, w, 0.000100950558f);
        p = fmaf(p, w, 0.00134934322f);
        p = fmaf(p, w, -0.00367342844f);
        p = fmaf(p, w, 0.00573950773f);
        p = fmaf(p, w, -0.0076224613f);
        p = fmaf(p, w, 0.00943887047f);
        p = fmaf(p, w, 1.00167406f);
        p = fmaf(p, w, 2.83297682f);
    }
    return p * x;
}

// jax.random.normal element at flat index idx (partitionable: bits = o0^o1).
__device__ __forceinline__ float jax_normal(uint32_t k0, uint32_t k1,
                                            uint32_t idx, uint32_t half) {
    uint32_t o0, o1, bits;
#if JAX_PARTITIONABLE
    threefry2x32(k0, k1, 0u, idx, o0, o1);
    bits = o0 ^ o1;
#else
    if (idx < half) { threefry2x32(k0, k1, idx, idx + half, o0, o1); bits = o0; }
    else            { threefry2x32(k0, k1, idx - half, idx, o0, o1); bits = o1; }
#endif
    uint32_t fb = (bits >> 9) | 0x3F800000u;
    float f = __uint_as_float(fb) - 1.0f;           // [0,1)
    const float lo = -0.99999994f;                  // nextafter(-1,0) f32
    float u = f * (1.0f - lo) + lo;                 // (1.0f - lo) == 2.0f
    u = fmaxf(lo, u);
    return 1.4142135623730951f * erfinv32(u);
}

// ---------------- SE(3) helpers, f32 (evolve path) ----------------
__device__ inline void se3_exp6(const float xi[6], float T[12]) {
    float tx = xi[0], ty = xi[1], tz = xi[2];
    float wx = xi[3], wy = xi[4], wz = xi[5];
    float nrm = sqrtf(wx * wx + wy * wy + wz * wz);
    float theta = fmaxf(nrm, 1e-8f);
    float kx = wx / theta, ky = wy / theta, kz = wz / theta;
    float K[9] = {0.0f, -kz, ky, kz, 0.0f, -kx, -ky, kx, 0.0f};
    float st = sinf(theta);
    float ct = 1.0f - cosf(theta);
    float KK[9];
    for (int i = 0; i < 3; i++)
        for (int j = 0; j < 3; j++)
            KK[i * 3 + j] = K[i * 3 + 0] * K[0 + j] + K[i * 3 + 1] * K[3 + j] + K[i * 3 + 2] * K[6 + j];
    float a = ct / theta;
    float bb = 1.0f - st / theta;
    float R[9], V[9];
    for (int i = 0; i < 3; i++)
        for (int j = 0; j < 3; j++) {
            float e = (i == j) ? 1.0f : 0.0f;
            R[i * 3 + j] = e + st * K[i * 3 + j] + ct * KK[i * 3 + j];
            V[i * 3 + j] = e + a * K[i * 3 + j] + bb * KK[i * 3 + j];
        }
    float t0 = V[0] * tx + V[1] * ty + V[2] * tz;
    float t1 = V[3] * tx + V[4] * ty + V[5] * tz;
    float t2 = V[6] * tx + V[7] * ty + V[8] * tz;
    T[0] = R[0]; T[1] = R[1]; T[2] = R[2];  T[3] = t0;
    T[4] = R[3]; T[5] = R[4]; T[6] = R[5];  T[7] = t1;
    T[8] = R[6]; T[9] = R[7]; T[10] = R[8]; T[11] = t2;
}

__device__ inline void compose44(const float dT[12], const float P[16], float Tn[16]) {
    for (int i = 0; i < 3; i++)
        for (int j = 0; j < 4; j++)
            Tn[i * 4 + j] = dT[i * 4 + 0] * P[0 + j] + dT[i * 4 + 1] * P[4 + j] +
                            dT[i * 4 + 2] * P[8 + j] + dT[i * 4 + 3] * P[12 + j];
    Tn[12] = 0.0f; Tn[13] = 0.0f; Tn[14] = 0.0f; Tn[15] = 1.0f;
}

__device__ inline void make_hypothesis(int m, const float* P, uint32_t hk0, uint32_t hk1,
                                       float Tn[16]) {
    float tn[3];
    for (int c = 0; c < 3; c++)
        tn[c] = jax_normal(hk0, hk1, (uint32_t)(m * 3 + c), 216u);
    int gi = m / 12, gj = m % 12;
    const float d2r = (float)(M_PI / 180.0);
    float xi[6] = {tn[0], tn[1], tn[2], 0.0f,
                   (float)(2 * gi - 11) * d2r, (float)(2 * gj - 11) * d2r};
    float dT[12];
    se3_exp6(xi, dT);
    compose44(dT, P, Tn);
}

// ---------------- SE(3) helpers, f64 (finalize path) ----------------
__device__ inline void se3_exp6d(const double xi[6], double T[12]) {
    double tx = xi[0], ty = xi[1], tz = xi[2];
    double wx = xi[3], wy = xi[4], wz = xi[5];
    double nrm = sqrt(wx * wx + wy * wy + wz * wz);
    double theta = fmax(nrm, 1e-8);
    double kx = wx / theta, ky = wy / theta, kz = wz / theta;
    double K[9] = {0.0, -kz, ky, kz, 0.0, -kx, -ky, kx, 0.0};
    double st = sin(theta);
    double ct = 1.0 - cos(theta);
    double KK[9];
    for (int i = 0; i < 3; i++)
        for (int j = 0; j < 3; j++)
            KK[i * 3 + j] = K[i * 3 + 0] * K[0 + j] + K[i * 3 + 1] * K[3 + j] + K[i * 3 + 2] * K[6 + j];
    double a = ct / theta;
    double bb = 1.0 - st / theta;
    double R[9], V[9];
    for (int i = 0; i < 3; i++)
        for (int j = 0; j < 3; j++) {
            double e = (i == j) ? 1.0 : 0.0;
            R[i * 3 + j] = e + st * K[i * 3 + j] + ct * KK[i * 3 + j];
            V[i * 3 + j] = e + a * K[i * 3 + j] + bb * KK[i * 3 + j];
        }
    double t0 = V[0] * tx + V[1] * ty + V[2] * tz;
    double t1 = V[3] * tx + V[4] * ty + V[5] * tz;
    double t2 = V[6] * tx + V[7] * ty + V[8] * tz;
    T[0] = R[0]; T[1] = R[1]; T[2] = R[2];  T[3] = t0;
    T[4] = R[3]; T[5] = R[4]; T[6] = R[5];  T[7] = t1;
    T[8] = R[6]; T[9] = R[7]; T[10] = R[8]; T[11] = t2;
}

__device__ inline void compose44d(const double dT[12], const double P[16], double Tn[16]) {
    for (int i = 0; i < 3; i++)
        for (int j = 0; j < 4; j++)
            Tn[i * 4 + j] = dT[i * 4 + 0] * P[0 + j] + dT[i * 4 + 1] * P[4 + j] +
                            dT[i * 4 + 2] * P[8 + j] + dT[i * 4 + 3] * P[12 + j];
    Tn[12] = 0.0; Tn[13] = 0.0; Tn[14] = 0.0; Tn[15] = 1.0;
}

__device__ inline void make_hypothesis_d(int m, const double* P, uint32_t hk0, uint32_t hk1,
                                         double Tn[16]) {
    float tn[3];
    for (int c = 0; c < 3; c++)
        tn[c] = jax_normal(hk0, hk1, (uint32_t)(m * 3 + c), 216u);
    int gi = m / 12, gj = m % 12;
    const float d2r = (float)(M_PI / 180.0);
    float pf = (float)(2 * gi - 11) * d2r;
    float yf = (float)(2 * gj - 11) * d2r;
    double xi[6] = {(double)tn[0], (double)tn[1], (double)tn[2], 0.0,
                    (double)pf, (double)yf};
    double dT[12];
    se3_exp6d(xi, dT);
    compose44d(dT, P, Tn);
}

struct IterKeys { uint32_t k0[9]; uint32_t k1[9]; float damping[9]; };

// ---------------- Transpose: D = q - r, NCHW -> NHWC (vectorized) ----------------
// Tile: TP pixels x C channels per block (256 threads). LDS [p][c], stride C+1.
template <int C, int HW, int TP>
__global__ __launch_bounds__(256) void diff_transpose_kernel(
    const float* __restrict__ q, const float* __restrict__ r,
    float* __restrict__ D) {
    __shared__ float tile[TP * (C + 1)];
    const int b = blockIdx.y;
    const int p0 = blockIdx.x * TP;
    const int tid = threadIdx.x;
    // phase 1: float4 over pixels (coalesced NCHW reads)
    constexpr int NV1 = C * (TP / 4);
    for (int idx = tid; idx < NV1; idx += 256) {
        int c = idx / (TP / 4);
        int p = (idx % (TP / 4)) * 4;
        size_t g = (size_t)(b * C + c) * HW + p0 + p;
        float4 qv = *(const float4*)(q + g);
        float4 rv = *(const float4*)(r + g);
        tile[(p + 0) * (C + 1) + c] = qv.x - rv.x;
        tile[(p + 1) * (C + 1) + c] = qv.y - rv.y;
        tile[(p + 2) * (C + 1) + c] = qv.z - rv.z;
        tile[(p + 3) * (C + 1) + c] = qv.w - rv.w;
    }
    __syncthreads();
    // phase 2: float4 over channels (coalesced NHWC writes)
    constexpr int NV2 = TP * (C / 4);
    for (int idx = tid; idx < NV2; idx += 256) {
        int p = idx / (C / 4);
        int c = (idx % (C / 4)) * 4;
        float4 o;
        o.x = tile[p * (C + 1) + c + 0];
        o.y = tile[p * (C + 1) + c + 1];
        o.z = tile[p * (C + 1) + c + 2];
        o.w = tile[p * (C + 1) + c + 3];
        *(float4*)(D + ((size_t)b * HW + p0 + p) * C + c) = o;
    }
}

// ---------------- Kernel 1 (NHWC-D): per-(b,m) full 9-iteration LM ----------------
// 1024 threads: g = tid>>9 selects channel half, pl = tid&511 is the point.
template <int C, int H, int W>
__device__ void run_level_nhwc(const float* __restrict__ Db,
                               const float* __restrict__ ub,
                               float fx, float fy, float cx, float cy,
                               const float* geoS, float* Tsh, float* red, float* resS,
                               float* stepS, float* out, int b, int m,
                               const IterKeys& iks, int firstIter, int niter) {
    const int tid = threadIdx.x;
    const int g = tid >> 9;
    const int pl = tid & 511;
    for (int it = 0; it < niter; it++) {
        const int iter = firstIter + it;
        float acc = 0.0f;
        if (pl < NPTS) {
            float px = geoS[pl * 3], py = geoS[pl * 3 + 1], pz = geoS[pl * 3 + 2];
            float X = Tsh[0] * px + Tsh[1] * py + Tsh[2]  * pz + Tsh[3];
            float Y = Tsh[4] * px + Tsh[5] * py + Tsh[6]  * pz + Tsh[7];
            float Z = Tsh[8] * px + Tsh[9] * py + Tsh[10] * pz + Tsh[11];
            float z = fmaxf(Z, 1e-6f);
            float uu = fx * (X / z) + cx;
            float vv = fy * (Y / z) + cy;
            float gx = 2.0f * uu / (float)(W - 1) - 1.0f;
            float gy = 2.0f * vv / (float)(H - 1) - 1.0f;
            float x = fminf(fmaxf(((gx + 1.0f) * (float)W - 1.0f) * 0.5f, 0.0f), (float)(W - 1));
            float y = fminf(fmaxf(((gy + 1.0f) * (float)H - 1.0f) * 0.5f, 0.0f), (float)(H - 1));
            float x0f = floorf(x), y0f = floorf(y);
            float x1f = fminf(x0f + 1.0f, (float)(W - 1));
            float y1f = fminf(y0f + 1.0f, (float)(H - 1));
            float wx = x - x0f, wy = y - y0f;
            int x0i = (int)x0f, x1i = (int)x1f, y0i = (int)y0f, y1i = (int)y1f;
            int i00 = y0i * W + x0i, i01 = y0i * W + x1i;
            int i10 = y1i * W + x0i, i11 = y1i * W + x1i;
            float w00 = (1.0f - wx) * (1.0f - wy), w01 = wx * (1.0f - wy);
            float w10 = (1.0f - wx) * wy,          w11 = wx * wy;
            float uval = ub[i00] * w00 + ub[i01] * w01 + ub[i10] * w10 + ub[i11] * w11;
            const float* p00 = Db + (size_t)i00 * C;
            const float* p01 = Db + (size_t)i01 * C;
            const float* p10 = Db + (size_t)i10 * C;
            const float* p11 = Db + (size_t)i11 * C;
            const int c0 = g * (C / 2);
            const int c1 = c0 + (C / 2);
#pragma unroll 4
            for (int c = c0; c < c1; c += 4) {
                float4 d00 = *(const float4*)(p00 + c);
                float4 d01 = *(const float4*)(p01 + c);
                float4 d10 = *(const float4*)(p10 + c);
                float4 d11 = *(const float4*)(p11 + c);
                float dx0 = w00 * d00.x + w01 * d01.x + w10 * d10.x + w11 * d11.x;
                float dx1 = w00 * d00.y + w01 * d01.y + w10 * d10.y + w11 * d11.y;
                float dx2 = w00 * d00.z + w01 * d01.z + w10 * d10.z + w11 * d11.z;
                float dx3 = w00 * d00.w + w01 * d01.w + w10 * d10.w + w11 * d11.w;
                acc += uval * (dx0 * dx0 + dx1 * dx1 + dx2 * dx2 + dx3 * dx3);
            }
        }
        // block reduction (16 waves)
        float v = acc;
        for (int off = 32; off > 0; off >>= 1) v += __shfl_down(v, off, 64);
        if ((tid & 63) == 0) red[tid >> 6] = v;
        __syncthreads();
        if (tid == 0) {
            float s = 0.0f;
            for (int w = 0; w < 16; w++) s += red[w];
            float res = s / 500.0f;
            *resS = res;
            if (iter == 8) out[128 + b * NM + m] = res;
        }
        __syncthreads();
        if (tid < 6) {
            uint32_t fi = (uint32_t)((b * NM + m) * 6 + tid);
            float nz = jax_normal(iks.k0[iter], iks.k1[iter], fi, 3456u);
            stepS[tid] = (((-iks.damping[iter]) * (*resS)) * nz) * 0.01f;
        }
        __syncthreads();
        if (tid == 0) {
            float xi[6];
            for (int j = 0; j < 6; j++) xi[j] = stepS[j];
            float dT[12];
            se3_exp6(xi, dT);
            float Told[16];
            for (int k = 0; k < 16; k++) Told[k] = Tsh[k];
            float Tn[16];
            compose44(dT, Told, Tn);
            for (int k = 0; k < 16; k++) Tsh[k] = Tn[k];
        }
        __syncthreads();
    }
}

__global__ __launch_bounds__(1024) void evolve_kernel_nhwc(
    const float* __restrict__ T_pred, const float* __restrict__ geo,
    const float* __restrict__ Kmat,
    const float* __restrict__ D0, const float* __restrict__ D1, const float* __restrict__ D2,
    const float* __restrict__ u0, const float* __restrict__ u1, const float* __restrict__ u2,
    float* __restrict__ Tws, float* __restrict__ out,
    uint32_t hk0, uint32_t hk1, IterKeys iks) {
    const int bm = blockIdx.x;
    const int b = bm >> 4;
    const int m = bm & 15;
    const int tid = threadIdx.x;

    __shared__ float Tsh[16];
    __shared__ float geoS[NPTS * 3];
    __shared__ float red[16];
    __shared__ float resS;
    __shared__ float stepS[6];

    for (int i = tid; i < NPTS * 3; i += 1024) geoS[i] = geo[b * NPTS * 3 + i];

    if (tid == 0) {
        float P[16];
        for (int k = 0; k < 16; k++) P[k] = T_pred[b * 16 + k];
        float Tn[16];
        make_hypothesis(m, P, hk0, hk1, Tn);
        for (int k = 0; k < 16; k++) Tsh[k] = Tn[k];
    }
    __syncthreads();

    float K00 = Kmat[b * 9 + 0], K02 = Kmat[b * 9 + 2];
    float K11 = Kmat[b * 9 + 4], K12 = Kmat[b * 9 + 5];

    run_level_nhwc<128, 48, 64>(D0 + (size_t)b * 48 * 64 * 128,
                                u0 + (size_t)b * 48 * 64,
                                K00 * 0.25f, K11 * 0.25f, K02 * 0.25f, K12 * 0.25f,
                                geoS, Tsh, red, &resS, stepS, out, b, m, iks, 0, 2);
    run_level_nhwc<64, 96, 128>(D1 + (size_t)b * 96 * 128 * 64,
                                u1 + (size_t)b * 96 * 128,
                                K00 * 0.5f, K11 * 0.5f, K02 * 0.5f, K12 * 0.5f,
                                geoS, Tsh, red, &resS, stepS, out, b, m, iks, 2, 3);
    run_level_nhwc<32, 192, 256>(D2 + (size_t)b * 192 * 256 * 32,
                                 u2 + (size_t)b * 192 * 256,
                                 K00, K11, K02, K12,
                                 geoS, Tsh, red, &resS, stepS, out, b, m, iks, 5, 4);

    if (tid < 16) Tws[(size_t)bm * 16 + tid] = Tsh[tid];
}

// ---------------- Fallback (NCHW gather, proven-correct) ----------------
template <int C, int H, int W>
__device__ void run_level_nchw(const float* __restrict__ qb, const float* __restrict__ rb,
                               const float* __restrict__ ub,
                               float fx, float fy, float cx, float cy,
                               const float* geoS, float* Tsh, float* red, float* resS,
                               float* stepS, float* out, int b, int m,
                               const IterKeys& iks, int firstIter, int niter) {
    const int tid = threadIdx.x;
    const int HW = H * W;
    for (int it = 0; it < niter; it++) {
        const int iter = firstIter + it;
        float acc = 0.0f;
        if (tid < NPTS) {
            float px = geoS[tid * 3], py = geoS[tid * 3 + 1], pz = geoS[tid * 3 + 2];
            float X = Tsh[0] * px + Tsh[1] * py + Tsh[2]  * pz + Tsh[3];
            float Y = Tsh[4] * px + Tsh[5] * py + Tsh[6]  * pz + Tsh[7];
            float Z = Tsh[8] * px + Tsh[9] * py + Tsh[10] * pz + Tsh[11];
            float z = fmaxf(Z, 1e-6f);
            float uu = fx * (X / z) + cx;
            float vv = fy * (Y / z) + cy;
            float gx = 2.0f * uu / (float)(W - 1) - 1.0f;
            float gy = 2.0f * vv / (float)(H - 1) - 1.0f;
            float x = fminf(fmaxf(((gx + 1.0f) * (float)W - 1.0f) * 0.5f, 0.0f), (float)(W - 1));
            float y = fminf(fmaxf(((gy + 1.0f) * (float)H - 1.0f) * 0.5f, 0.0f), (float)(H - 1));
            float x0f = floorf(x), y0f = floorf(y);
            float x1f = fminf(x0f + 1.0f, (float)(W - 1));
            float y1f = fminf(y0f + 1.0f, (float)(H - 1));
            float wx = x - x0f, wy = y - y0f;
            int x0i = (int)x0f, x1i = (int)x1f, y0i = (int)y0f, y1i = (int)y1f;
            int i00 = y0i * W + x0i, i01 = y0i * W + x1i;
            int i10 = y1i * W + x0i, i11 = y1i * W + x1i;
            float w00 = (1.0f - wx) * (1.0f - wy), w01 = wx * (1.0f - wy);
            float w10 = (1.0f - wx) * wy,          w11 = wx * wy;
            float uval = ub[i00] * w00 + ub[i01] * w01 + ub[i10] * w10 + ub[i11] * w11;
            const float* qp = qb;
            const float* rp = rb;
#pragma unroll 4
            for (int c = 0; c < C; c++) {
                float qv = qp[i00] * w00 + qp[i01] * w01 + qp[i10] * w10 + qp[i11] * w11;
                float rv = rp[i00] * w00 + rp[i01] * w01 + rp[i10] * w10 + rp[i11] * w11;
                float d = qv - rv;
                acc += uval * (d * d);
                qp += HW; rp += HW;
            }
        }
        float v = acc;
        for (int off = 32; off > 0; off >>= 1) v += __shfl_down(v, off, 64);
        if ((tid & 63) == 0) red[tid >> 6] = v;
        __syncthreads();
        if (tid == 0) {
            float s = 0.0f;
            for (int w = 0; w < 8; w++) s += red[w];
            float res = s / 500.0f;
            *resS = res;
            if (iter == 8) out[128 + b * NM + m] = res;
        }
        __syncthreads();
        if (tid < 6) {
            uint32_t fi = (uint32_t)((b * NM + m) * 6 + tid);
            float nz = jax_normal(iks.k0[iter], iks.k1[iter], fi, 3456u);
            stepS[tid] = (((-iks.damping[iter]) * (*resS)) * nz) * 0.01f;
        }
        __syncthreads();
        if (tid == 0) {
            float xi[6];
            for (int j = 0; j < 6; j++) xi[j] = stepS[j];
            float dT[12];
            se3_exp6(xi, dT);
            float Told[16];
            for (int k = 0; k < 16; k++) Told[k] = Tsh[k];
            float Tn[16];
            compose44(dT, Told, Tn);
            for (int k = 0; k < 16; k++) Tsh[k] = Tn[k];
        }
        __syncthreads();
    }
}

__global__ __launch_bounds__(512) void evolve_kernel_nchw(
    const float* __restrict__ T_pred, const float* __restrict__ geo,
    const float* __restrict__ Kmat,
    const float* __restrict__ q0, const float* __restrict__ q1, const float* __restrict__ q2,
    const float* __restrict__ r0, const float* __restrict__ r1, const float* __restrict__ r2,
    const float* __restrict__ u0, const float* __restrict__ u1, const float* __restrict__ u2,
    float* __restrict__ Tws, float* __restrict__ out,
    uint32_t hk0, uint32_t hk1, IterKeys iks) {
    const int bm = blockIdx.x;
    const int b = bm >> 4;
    const int m = bm & 15;
    const int tid = threadIdx.x;

    __shared__ float Tsh[16];
    __shared__ float geoS[NPTS * 3];
    __shared__ float red[8];
    __shared__ float resS;
    __shared__ float stepS[6];

    for (int i = tid; i < NPTS * 3; i += 512) geoS[i] = geo[b * NPTS * 3 + i];

    if (tid == 0) {
        float P[16];
        for (int k = 0; k < 16; k++) P[k] = T_pred[b * 16 + k];
        float Tn[16];
        make_hypothesis(m, P, hk0, hk1, Tn);
        for (int k = 0; k < 16; k++) Tsh[k] = Tn[k];
    }
    __syncthreads();

    float K00 = Kmat[b * 9 + 0], K02 = Kmat[b * 9 + 2];
    float K11 = Kmat[b * 9 + 4], K12 = Kmat[b * 9 + 5];

    run_level_nchw<128, 48, 64>(q0 + (size_t)b * 128 * 48 * 64, r0 + (size_t)b * 128 * 48 * 64,
                                u0 + (size_t)b * 48 * 64,
                                K00 * 0.25f, K11 * 0.25f, K02 * 0.25f, K12 * 0.25f,
                                geoS, Tsh, red, &resS, stepS, out, b, m, iks, 0, 2);
    run_level_nchw<64, 96, 128>(q1 + (size_t)b * 64 * 96 * 128, r1 + (size_t)b * 64 * 96 * 128,
                                u1 + (size_t)b * 96 * 128,
                                K00 * 0.5f, K11 * 0.5f, K02 * 0.5f, K12 * 0.5f,
                                geoS, Tsh, red, &resS, stepS, out, b, m, iks, 2, 3);
    run_level_nchw<32, 192, 256>(q2 + (size_t)b * 32 * 192 * 256, r2 + (size_t)b * 32 * 192 * 256,
                                 u2 + (size_t)b * 192 * 256,
                                 K00, K11, K02, K12,
                                 geoS, Tsh, red, &resS, stepS, out, b, m, iks, 5, 4);

    if (tid < 16) Tws[(size_t)bm * 16 + tid] = Tsh[tid];
}

// ---------------- Kernel 2: geodesic prior + argmin + T_best (f64 path) ----------------
__global__ __launch_bounds__(192) void finalize_kernel(
    const float* __restrict__ T_pred, const float* __restrict__ Tws,
    float* __restrict__ out, uint32_t hk0, uint32_t hk1) {
    const int b = blockIdx.x;
    const int tid = threadIdx.x;
    __shared__ double Pm[16];
    __shared__ double inv[12];
    __shared__ double totals[NM];
    __shared__ int bestm_sh;

    if (tid < 16) Pm[tid] = (double)T_pred[b * 16 + tid];
    __syncthreads();
    if (tid == 0) {
        for (int k = 0; k < 3; k++)
            for (int j = 0; j < 3; j++) inv[k * 4 + j] = Pm[j * 4 + k];
        for (int k = 0; k < 3; k++)
            inv[k * 4 + 3] = -(Pm[0 * 4 + k] * Pm[3] + Pm[1 * 4 + k] * Pm[7] + Pm[2 * 4 + k] * Pm[11]);
    }
    __syncthreads();

    double Tc[16];
    if (tid < NM) {
        double cost;
        if (tid < NM16) {
            for (int k = 0; k < 16; k++) Tc[k] = (double)Tws[(size_t)(b * NM16 + tid) * 16 + k];
            cost = (double)out[128 + b * NM + tid];
        } else {
            make_hypothesis_d(tid, Pm, hk0, hk1, Tc);
            cost = 0.0;
            out[128 + b * NM + tid] = 0.0f;
        }
        double Tr[12];
        for (int i = 0; i < 3; i++)
            for (int j = 0; j < 4; j++)
                Tr[i * 4 + j] = Tc[i * 4 + 0] * inv[0 + j] + Tc[i * 4 + 1] * inv[4 + j] +
                                Tc[i * 4 + 2] * inv[8 + j] + ((j == 3) ? Tc[i * 4 + 3] : 0.0);
        double cos_a = (Tr[0] + Tr[5] + Tr[10] - 1.0) * 0.5;
        cos_a = fmin(fmax(cos_a, -1.0 + 1e-7), 1.0 - 1e-7);
        double theta = acos(cos_a);
        double th = fmax(theta, 1e-8);
        double s2 = 2.0 * fmax(sin(th), 1e-8);
        double w0 = (Tr[2 * 4 + 1] - Tr[1 * 4 + 2]) / s2 * th;
        double w1 = (Tr[0 * 4 + 2] - Tr[2 * 4 + 0]) / s2 * th;
        double w2 = (Tr[1 * 4 + 0] - Tr[0 * 4 + 1]) / s2 * th;
        double t0 = Tr[3], t1 = Tr[7], t2 = Tr[11];
        double geod = sqrt(t0 * t0 + t1 * t1 + t2 * t2 + w0 * w0 + w1 * w1 + w2 * w2);
        totals[tid] = cost + geod;
    }
    __syncthreads();
    if (tid == 0) {
        int best = 0;
        double bv = totals[0];
        for (int mm = 1; mm < NM; mm++) {
            if (totals[mm] < bv) { bv = totals[mm]; best = mm; }
        }
        bestm_sh = best;
    }
    __syncthreads();
    if (tid == bestm_sh) {
        for (int k = 0; k < 16; k++) out[b * 16 + k] = (float)Tc[k];
    }
}

extern "C" void kernel_launch(void* const* d_in, const int* in_sizes, int n_in,
                              void* d_out, int out_size, void* d_ws, size_t ws_size,
                              hipStream_t stream) {
    (void)in_sizes; (void)n_in; (void)out_size;
    const float* T_pred = (const float*)d_in[0];
    const float* geo    = (const float*)d_in[1];
    const float* K      = (const float*)d_in[2];
    const float* q0 = (const float*)d_in[3];
    const float* q1 = (const float*)d_in[4];
    const float* q2 = (const float*)d_in[5];
    const float* r0 = (const float*)d_in[6];
    const float* r1 = (const float*)d_in[7];
    const float* r2 = (const float*)d_in[8];
    const float* u0 = (const float*)d_in[9];
    const float* u1 = (const float*)d_in[10];
    const float* u2 = (const float*)d_in[11];
    float* out = (float*)d_out;   // [0:128] T_best (8,4,4); [128:1280] costs (8,144)

    // workspace layout: Tws (2048 f) | D0 | D1 | D2
    float* Tws = (float*)d_ws;
    const size_t nD0 = (size_t)NB * 48 * 64 * 128;    // 3,145,728
    const size_t nD1 = (size_t)NB * 96 * 128 * 64;    // 6,291,456
    const size_t nD2 = (size_t)NB * 192 * 256 * 32;   // 12,582,912
    float* D0 = Tws + 2048;
    float* D1 = D0 + nD0;
    float* D2 = D1 + nD1;
    const size_t need = (2048 + nD0 + nD1 + nD2) * sizeof(float);

    // host-side key derivation (pure integer math; graph-capture safe)
    uint32_t hk0, hk1;
    threefry2x32(0u, 42u, 0u, 0u, hk0, hk1);  // fold_in(key(42), 0)
    IterKeys iks;
    const int seeds[9] = {100, 101, 110, 111, 112, 120, 121, 122, 123};
    const float damp[9] = {0.001f, 0.001f, 0.0005f, 0.0005f, 0.0005f,
                           0.00025f, 0.00025f, 0.00025f, 0.00025f};
    for (int i = 0; i < 9; i++) {
        threefry2x32(0u, 42u, 0u, (uint32_t)seeds[i], iks.k0[i], iks.k1[i]);
        iks.damping[i] = damp[i];
    }

    if (ws_size >= need) {
        diff_transpose_kernel<128, 48 * 64, 64>
            <<<dim3(48 * 64 / 64, NB), dim3(256), 0, stream>>>(q0, r0, D0);
        diff_transpose_kernel<64, 96 * 128, 128>
            <<<dim3(96 * 128 / 128, NB), dim3(256), 0, stream>>>(q1, r1, D1);
        diff_transpose_kernel<32, 192 * 256, 256>
            <<<dim3(192 * 256 / 256, NB), dim3(256), 0, stream>>>(q2, r2, D2);
        evolve_kernel_nhwc<<<dim3(NB * NM16), dim3(1024), 0, stream>>>(
            T_pred, geo, K, D0, D1, D2, u0, u1, u2, Tws, out, hk0, hk1, iks);
    } else {
        evolve_kernel_nchw<<<dim3(NB * NM16), dim3(512), 0, stream>>>(
            T_pred, geo, K, q0, q1, q2, r0, r1, r2, u0, u1, u2, Tws, out, hk0, hk1, iks);
    }
    finalize_kernel<<<dim3(NB), dim3(192), 0, stream>>>(T_pred, Tws, out, hk0, hk1);
}

// Round 6
// 392.813 us; speedup vs baseline: 1.1795x; 1.1795x over previous
//
#include <hip/hip_runtime.h>
#include <stdint.h>
#include <math.h>

#define JAX_PARTITIONABLE 1

#define NB 8
#define NM 144
#define NM16 16
#define NPTS 500
#define GP 16   // floats per pixel Gram record (10 used, padded to one 64B line)

// ---------------- Threefry-2x32 (JAX-exact) ----------------
__host__ __device__ __forceinline__ uint32_t rotl32(uint32_t x, int r) {
    return (x << r) | (x >> (32 - r));
}

__host__ __device__ inline void threefry2x32(uint32_t k0, uint32_t k1,
                                             uint32_t x0, uint32_t x1,
                                             uint32_t& o0, uint32_t& o1) {
    uint32_t ks2 = k0 ^ k1 ^ 0x1BD11BDAu;
    x0 += k0; x1 += k1;
    const int RA[4] = {13, 15, 26, 6};
    const int RB[4] = {17, 29, 16, 24};
#define R4(ROT) { x0 += x1; x1 = rotl32(x1, ROT[0]); x1 ^= x0; \
                  x0 += x1; x1 = rotl32(x1, ROT[1]); x1 ^= x0; \
                  x0 += x1; x1 = rotl32(x1, ROT[2]); x1 ^= x0; \
                  x0 += x1; x1 = rotl32(x1, ROT[3]); x1 ^= x0; }
    R4(RA); x0 += k1;  x1 += ks2 + 1u;
    R4(RB); x0 += ks2; x1 += k0 + 2u;
    R4(RA); x0 += k0;  x1 += k1 + 3u;
    R4(RB); x0 += k1;  x1 += ks2 + 4u;
    R4(RA); x0 += ks2; x1 += k0 + 5u;
#undef R4
    o0 = x0; o1 = x1;
}

// XLA f32 erf_inv (Giles polynomial pair)
__device__ __forceinline__ float erfinv32(float x) {
    float w = -log1pf(-x * x);
    float p;
    if (w < 5.0f) {
        w = w - 2.5f;
        p = 2.81022636e-08f;
        p = fmaf(p, w, 3.43273939e-07f);
        p = fmaf(p, w, -3.5233877e-06f);
        p = fmaf(p, w, -4.39150654e-06f);
        p = fmaf(p, w, 0.00021858087f);
        p = fmaf(p, w, -0.00125372503f);
        p = fmaf(p, w, -0.00417768164f);
        p = fmaf(p, w, 0.246640727f);
        p = fmaf(p, w, 1.50140941f);
    } else {
        w = sqrtf(w) - 3.0f;
        p = -0.000200214257f;
        p = fmaf(p, w, 0.000100950558f);
        p = fmaf(p, w, 0.00134934322f);
        p = fmaf(p, w, -0.00367342844f);
        p = fmaf(p, w, 0.00573950773f);
        p = fmaf(p, w, -0.0076224613f);
        p = fmaf(p, w, 0.00943887047f);
        p = fmaf(p, w, 1.00167406f);
        p = fmaf(p, w, 2.83297682f);
    }
    return p * x;
}

// jax.random.normal element at flat index idx (partitionable: bits = o0^o1).
__device__ __forceinline__ float jax_normal(uint32_t k0, uint32_t k1,
                                            uint32_t idx, uint32_t half) {
    uint32_t o0, o1, bits;
#if JAX_PARTITIONABLE
    threefry2x32(k0, k1, 0u, idx, o0, o1);
    bits = o0 ^ o1;
#else
    if (idx < half) { threefry2x32(k0, k1, idx, idx + half, o0, o1); bits = o0; }
    else            { threefry2x32(k0, k1, idx - half, idx, o0, o1); bits = o1; }
#endif
    uint32_t fb = (bits >> 9) | 0x3F800000u;
    float f = __uint_as_float(fb) - 1.0f;           // [0,1)
    const float lo = -0.99999994f;                  // nextafter(-1,0) f32
    float u = f * (1.0f - lo) + lo;                 // (1.0f - lo) == 2.0f
    u = fmaxf(lo, u);
    return 1.4142135623730951f * erfinv32(u);
}

// ---------------- SE(3) helpers, f32 (evolve path) ----------------
__device__ inline void se3_exp6(const float xi[6], float T[12]) {
    float tx = xi[0], ty = xi[1], tz = xi[2];
    float wx = xi[3], wy = xi[4], wz = xi[5];
    float nrm = sqrtf(wx * wx + wy * wy + wz * wz);
    float theta = fmaxf(nrm, 1e-8f);
    float kx = wx / theta, ky = wy / theta, kz = wz / theta;
    float K[9] = {0.0f, -kz, ky, kz, 0.0f, -kx, -ky, kx, 0.0f};
    float st = sinf(theta);
    float ct = 1.0f - cosf(theta);
    float KK[9];
    for (int i = 0; i < 3; i++)
        for (int j = 0; j < 3; j++)
            KK[i * 3 + j] = K[i * 3 + 0] * K[0 + j] + K[i * 3 + 1] * K[3 + j] + K[i * 3 + 2] * K[6 + j];
    float a = ct / theta;
    float bb = 1.0f - st / theta;
    float R[9], V[9];
    for (int i = 0; i < 3; i++)
        for (int j = 0; j < 3; j++) {
            float e = (i == j) ? 1.0f : 0.0f;
            R[i * 3 + j] = e + st * K[i * 3 + j] + ct * KK[i * 3 + j];
            V[i * 3 + j] = e + a * K[i * 3 + j] + bb * KK[i * 3 + j];
        }
    float t0 = V[0] * tx + V[1] * ty + V[2] * tz;
    float t1 = V[3] * tx + V[4] * ty + V[5] * tz;
    float t2 = V[6] * tx + V[7] * ty + V[8] * tz;
    T[0] = R[0]; T[1] = R[1]; T[2] = R[2];  T[3] = t0;
    T[4] = R[3]; T[5] = R[4]; T[6] = R[5];  T[7] = t1;
    T[8] = R[6]; T[9] = R[7]; T[10] = R[8]; T[11] = t2;
}

__device__ inline void compose44(const float dT[12], const float P[16], float Tn[16]) {
    for (int i = 0; i < 3; i++)
        for (int j = 0; j < 4; j++)
            Tn[i * 4 + j] = dT[i * 4 + 0] * P[0 + j] + dT[i * 4 + 1] * P[4 + j] +
                            dT[i * 4 + 2] * P[8 + j] + dT[i * 4 + 3] * P[12 + j];
    Tn[12] = 0.0f; Tn[13] = 0.0f; Tn[14] = 0.0f; Tn[15] = 1.0f;
}

__device__ inline void make_hypothesis(int m, const float* P, uint32_t hk0, uint32_t hk1,
                                       float Tn[16]) {
    float tn[3];
    for (int c = 0; c < 3; c++)
        tn[c] = jax_normal(hk0, hk1, (uint32_t)(m * 3 + c), 216u);
    int gi = m / 12, gj = m % 12;
    const float d2r = (float)(M_PI / 180.0);
    float xi[6] = {tn[0], tn[1], tn[2], 0.0f,
                   (float)(2 * gi - 11) * d2r, (float)(2 * gj - 11) * d2r};
    float dT[12];
    se3_exp6(xi, dT);
    compose44(dT, P, Tn);
}

// ---------------- SE(3) helpers, f64 (finalize path) ----------------
__device__ inline void se3_exp6d(const double xi[6], double T[12]) {
    double tx = xi[0], ty = xi[1], tz = xi[2];
    double wx = xi[3], wy = xi[4], wz = xi[5];
    double nrm = sqrt(wx * wx + wy * wy + wz * wz);
    double theta = fmax(nrm, 1e-8);
    double kx = wx / theta, ky = wy / theta, kz = wz / theta;
    double K[9] = {0.0, -kz, ky, kz, 0.0, -kx, -ky, kx, 0.0};
    double st = sin(theta);
    double ct = 1.0 - cos(theta);
    double KK[9];
    for (int i = 0; i < 3; i++)
        for (int j = 0; j < 3; j++)
            KK[i * 3 + j] = K[i * 3 + 0] * K[0 + j] + K[i * 3 + 1] * K[3 + j] + K[i * 3 + 2] * K[6 + j];
    double a = ct / theta;
    double bb = 1.0 - st / theta;
    double R[9], V[9];
    for (int i = 0; i < 3; i++)
        for (int j = 0; j < 3; j++) {
            double e = (i == j) ? 1.0 : 0.0;
            R[i * 3 + j] = e + st * K[i * 3 + j] + ct * KK[i * 3 + j];
            V[i * 3 + j] = e + a * K[i * 3 + j] + bb * KK[i * 3 + j];
        }
    double t0 = V[0] * tx + V[1] * ty + V[2] * tz;
    double t1 = V[3] * tx + V[4] * ty + V[5] * tz;
    double t2 = V[6] * tx + V[7] * ty + V[8] * tz;
    T[0] = R[0]; T[1] = R[1]; T[2] = R[2];  T[3] = t0;
    T[4] = R[3]; T[5] = R[4]; T[6] = R[5];  T[7] = t1;
    T[8] = R[6]; T[9] = R[7]; T[10] = R[8]; T[11] = t2;
}

__device__ inline void compose44d(const double dT[12], const double P[16], double Tn[16]) {
    for (int i = 0; i < 3; i++)
        for (int j = 0; j < 4; j++)
            Tn[i * 4 + j] = dT[i * 4 + 0] * P[0 + j] + dT[i * 4 + 1] * P[4 + j] +
                            dT[i * 4 + 2] * P[8 + j] + dT[i * 4 + 3] * P[12 + j];
    Tn[12] = 0.0; Tn[13] = 0.0; Tn[14] = 0.0; Tn[15] = 1.0;
}

__device__ inline void make_hypothesis_d(int m, const double* P, uint32_t hk0, uint32_t hk1,
                                         double Tn[16]) {
    float tn[3];
    for (int c = 0; c < 3; c++)
        tn[c] = jax_normal(hk0, hk1, (uint32_t)(m * 3 + c), 216u);
    int gi = m / 12, gj = m % 12;
    const float d2r = (float)(M_PI / 180.0);
    float pf = (float)(2 * gi - 11) * d2r;
    float yf = (float)(2 * gj - 11) * d2r;
    double xi[6] = {(double)tn[0], (double)tn[1], (double)tn[2], 0.0,
                    (double)pf, (double)yf};
    double dT[12];
    se3_exp6d(xi, dT);
    compose44d(dT, P, Tn);
}

struct IterKeys { uint32_t k0[9]; uint32_t k1[9]; float damping[9]; };

// ---------------- Gram builder: per-pixel 2x2-window Gram over channels ----------
// For anchor (x,y): taps t00=(x,y), t01=(x1,y), t10=(x,y1), t11=(x1,y1) with
// x1=min(x+1,W-1), y1=min(y+1,H-1); d = q-r.
// Record (GP floats): [M00,M01,M02,M03, M11,M12,M13,M22, M23,M33, pad...]
// Block: 256 threads, 4 anchor rows x W cols; PXT = 4*W/256 pixels/thread.
template <int C, int H, int W, int PXT>
__global__ __launch_bounds__(256) void gram_kernel(
    const float* __restrict__ q, const float* __restrict__ r,
    float* __restrict__ G) {
    __shared__ float dsh[5 * W];   // rows y0..y0+4 of current channel's diff
    const int b = blockIdx.y;
    const int y0 = blockIdx.x * 4;
    const int tid = threadIdx.x;

    float acc[PXT][10];
#pragma unroll
    for (int k = 0; k < PXT; k++)
#pragma unroll
        for (int i = 0; i < 10; i++) acc[k][i] = 0.0f;

    for (int c = 0; c < C; c++) {
        const size_t base = ((size_t)(b * C + c)) * H;
        // load 5 rows (row y0+j clamped to H-1), float4 over columns
        constexpr int NV = 5 * (W / 4);
        for (int idx = tid; idx < NV; idx += 256) {
            int j = idx / (W / 4);
            int px4 = (idx % (W / 4)) * 4;
            int ry = y0 + j; if (ry > H - 1) ry = H - 1;
            size_t g = (base + ry) * W + px4;
            float4 qv = *(const float4*)(q + g);
            float4 rv = *(const float4*)(r + g);
            dsh[j * W + px4 + 0] = qv.x - rv.x;
            dsh[j * W + px4 + 1] = qv.y - rv.y;
            dsh[j * W + px4 + 2] = qv.z - rv.z;
            dsh[j * W + px4 + 3] = qv.w - rv.w;
        }
        __syncthreads();
#pragma unroll
        for (int k = 0; k < PXT; k++) {
            int px = tid + k * 256;          // in [0, 4*W)
            int row = px / W;
            int x = px % W;
            int x1 = (x + 1 < W) ? x + 1 : W - 1;
            float f0  = dsh[row * W + x];
            float f0r = dsh[row * W + x1];
            float f1  = dsh[(row + 1) * W + x];
            float f1r = dsh[(row + 1) * W + x1];
            acc[k][0] = fmaf(f0,  f0,  acc[k][0]);   // M00
            acc[k][1] = fmaf(f0,  f0r, acc[k][1]);   // M01
            acc[k][2] = fmaf(f0,  f1,  acc[k][2]);   // M02
            acc[k][3] = fmaf(f0,  f1r, acc[k][3]);   // M03
            acc[k][4] = fmaf(f0r, f0r, acc[k][4]);   // M11
            acc[k][5] = fmaf(f0r, f1,  acc[k][5]);   // M12
            acc[k][6] = fmaf(f0r, f1r, acc[k][6]);   // M13
            acc[k][7] = fmaf(f1,  f1,  acc[k][7]);   // M22
            acc[k][8] = fmaf(f1,  f1r, acc[k][8]);   // M23
            acc[k][9] = fmaf(f1r, f1r, acc[k][9]);   // M33
        }
        __syncthreads();
    }
#pragma unroll
    for (int k = 0; k < PXT; k++) {
        int px = tid + k * 256;
        int y = y0 + px / W;
        int x = px % W;
        size_t base = (((size_t)b * H + y) * W + x) * GP;
        float4 g0 = {acc[k][0], acc[k][1], acc[k][2], acc[k][3]};
        float4 g1 = {acc[k][4], acc[k][5], acc[k][6], acc[k][7]};
        float4 g2 = {acc[k][8], acc[k][9], 0.0f, 0.0f};
        *(float4*)(G + base + 0) = g0;
        *(float4*)(G + base + 4) = g1;
        *(float4*)(G + base + 8) = g2;
    }
}

// ---------------- Kernel 1 (Gram): per-(b,m) full 9-iteration LM ----------------
template <int H, int W>
__device__ void run_level_gram(const float* __restrict__ Gb,   // Gram for batch b
                               const float* __restrict__ ub,
                               float fx, float fy, float cx, float cy,
                               const float* geoS, float* Tsh, float* red, float* resS,
                               float* stepS, float* out, int b, int m,
                               const IterKeys& iks, int firstIter, int niter) {
    const int tid = threadIdx.x;
    for (int it = 0; it < niter; it++) {
        const int iter = firstIter + it;
        float acc = 0.0f;
        if (tid < NPTS) {
            float px = geoS[tid * 3], py = geoS[tid * 3 + 1], pz = geoS[tid * 3 + 2];
            float X = Tsh[0] * px + Tsh[1] * py + Tsh[2]  * pz + Tsh[3];
            float Y = Tsh[4] * px + Tsh[5] * py + Tsh[6]  * pz + Tsh[7];
            float Z = Tsh[8] * px + Tsh[9] * py + Tsh[10] * pz + Tsh[11];
            float z = fmaxf(Z, 1e-6f);
            float uu = fx * (X / z) + cx;
            float vv = fy * (Y / z) + cy;
            float gx = 2.0f * uu / (float)(W - 1) - 1.0f;
            float gy = 2.0f * vv / (float)(H - 1) - 1.0f;
            float x = fminf(fmaxf(((gx + 1.0f) * (float)W - 1.0f) * 0.5f, 0.0f), (float)(W - 1));
            float y = fminf(fmaxf(((gy + 1.0f) * (float)H - 1.0f) * 0.5f, 0.0f), (float)(H - 1));
            float x0f = floorf(x), y0f = floorf(y);
            float x1f = fminf(x0f + 1.0f, (float)(W - 1));
            float y1f = fminf(y0f + 1.0f, (float)(H - 1));
            float wx = x - x0f, wy = y - y0f;
            int x0i = (int)x0f, x1i = (int)x1f, y0i = (int)y0f, y1i = (int)y1f;
            int i00 = y0i * W + x0i, i01 = y0i * W + x1i;
            int i10 = y1i * W + x0i, i11 = y1i * W + x1i;
            float w00 = (1.0f - wx) * (1.0f - wy), w01 = wx * (1.0f - wy);
            float w10 = (1.0f - wx) * wy,          w11 = wx * wy;
            float uval = ub[i00] * w00 + ub[i01] * w01 + ub[i10] * w10 + ub[i11] * w11;
            const float* Gp = Gb + (size_t)i00 * GP;
            float4 g0 = *(const float4*)(Gp + 0);
            float4 g1 = *(const float4*)(Gp + 4);
            float4 g2 = *(const float4*)(Gp + 8);
            // sum_c (w00 d00 + w01 d01 + w10 d10 + w11 d11)^2 = w^T M w
            float val = w00 * w00 * g0.x + w01 * w01 * g1.x +
                        w10 * w10 * g1.w + w11 * w11 * g2.y +
                        2.0f * (w00 * w01 * g0.y + w00 * w10 * g0.z + w00 * w11 * g0.w +
                                w01 * w10 * g1.y + w01 * w11 * g1.z + w10 * w11 * g2.x);
            acc = uval * val;
        }
        // block reduction (8 waves)
        float v = acc;
        for (int off = 32; off > 0; off >>= 1) v += __shfl_down(v, off, 64);
        if ((tid & 63) == 0) red[tid >> 6] = v;
        __syncthreads();
        if (tid == 0) {
            float s = 0.0f;
            for (int w = 0; w < 8; w++) s += red[w];
            float res = s / 500.0f;
            *resS = res;
            if (iter == 8) out[128 + b * NM + m] = res;
        }
        __syncthreads();
        if (tid < 6) {
            uint32_t fi = (uint32_t)((b * NM + m) * 6 + tid);
            float nz = jax_normal(iks.k0[iter], iks.k1[iter], fi, 3456u);
            stepS[tid] = (((-iks.damping[iter]) * (*resS)) * nz) * 0.01f;
        }
        __syncthreads();
        if (tid == 0) {
            float xi[6];
            for (int j = 0; j < 6; j++) xi[j] = stepS[j];
            float dT[12];
            se3_exp6(xi, dT);
            float Told[16];
            for (int k = 0; k < 16; k++) Told[k] = Tsh[k];
            float Tn[16];
            compose44(dT, Told, Tn);
            for (int k = 0; k < 16; k++) Tsh[k] = Tn[k];
        }
        __syncthreads();
    }
}

__global__ __launch_bounds__(512) void evolve_kernel_gram(
    const float* __restrict__ T_pred, const float* __restrict__ geo,
    const float* __restrict__ Kmat,
    const float* __restrict__ G0, const float* __restrict__ G1, const float* __restrict__ G2,
    const float* __restrict__ u0, const float* __restrict__ u1, const float* __restrict__ u2,
    float* __restrict__ Tws, float* __restrict__ out,
    uint32_t hk0, uint32_t hk1, IterKeys iks) {
    const int bm = blockIdx.x;
    // XCD swizzle: blockIdx % 8 selects XCD (round-robin heuristic); putting all
    // 16 m-blocks of one batch on one XCD keeps that batch's G slice L2-resident.
    const int b = bm & 7;
    const int m = bm >> 3;
    const int tid = threadIdx.x;

    __shared__ float Tsh[16];
    __shared__ float geoS[NPTS * 3];
    __shared__ float red[8];
    __shared__ float resS;
    __shared__ float stepS[6];

    for (int i = tid; i < NPTS * 3; i += 512) geoS[i] = geo[b * NPTS * 3 + i];

    if (tid == 0) {
        float P[16];
        for (int k = 0; k < 16; k++) P[k] = T_pred[b * 16 + k];
        float Tn[16];
        make_hypothesis(m, P, hk0, hk1, Tn);
        for (int k = 0; k < 16; k++) Tsh[k] = Tn[k];
    }
    __syncthreads();

    float K00 = Kmat[b * 9 + 0], K02 = Kmat[b * 9 + 2];
    float K11 = Kmat[b * 9 + 4], K12 = Kmat[b * 9 + 5];

    run_level_gram<48, 64>(G0 + (size_t)b * 48 * 64 * GP, u0 + (size_t)b * 48 * 64,
                           K00 * 0.25f, K11 * 0.25f, K02 * 0.25f, K12 * 0.25f,
                           geoS, Tsh, red, &resS, stepS, out, b, m, iks, 0, 2);
    run_level_gram<96, 128>(G1 + (size_t)b * 96 * 128 * GP, u1 + (size_t)b * 96 * 128,
                            K00 * 0.5f, K11 * 0.5f, K02 * 0.5f, K12 * 0.5f,
                            geoS, Tsh, red, &resS, stepS, out, b, m, iks, 2, 3);
    run_level_gram<192, 256>(G2 + (size_t)b * 192 * 256 * GP, u2 + (size_t)b * 192 * 256,
                             K00, K11, K02, K12,
                             geoS, Tsh, red, &resS, stepS, out, b, m, iks, 5, 4);

    if (tid < 16) Tws[(size_t)(b * NM16 + m) * 16 + tid] = Tsh[tid];
}

// ---------------- Fallback (NCHW gather, proven-correct) ----------------
template <int C, int H, int W>
__device__ void run_level_nchw(const float* __restrict__ qb, const float* __restrict__ rb,
                               const float* __restrict__ ub,
                               float fx, float fy, float cx, float cy,
                               const float* geoS, float* Tsh, float* red, float* resS,
                               float* stepS, float* out, int b, int m,
                               const IterKeys& iks, int firstIter, int niter) {
    const int tid = threadIdx.x;
    const int HW = H * W;
    for (int it = 0; it < niter; it++) {
        const int iter = firstIter + it;
        float acc = 0.0f;
        if (tid < NPTS) {
            float px = geoS[tid * 3], py = geoS[tid * 3 + 1], pz = geoS[tid * 3 + 2];
            float X = Tsh[0] * px + Tsh[1] * py + Tsh[2]  * pz + Tsh[3];
            float Y = Tsh[4] * px + Tsh[5] * py + Tsh[6]  * pz + Tsh[7];
            float Z = Tsh[8] * px + Tsh[9] * py + Tsh[10] * pz + Tsh[11];
            float z = fmaxf(Z, 1e-6f);
            float uu = fx * (X / z) + cx;
            float vv = fy * (Y / z) + cy;
            float gx = 2.0f * uu / (float)(W - 1) - 1.0f;
            float gy = 2.0f * vv / (float)(H - 1) - 1.0f;
            float x = fminf(fmaxf(((gx + 1.0f) * (float)W - 1.0f) * 0.5f, 0.0f), (float)(W - 1));
            float y = fminf(fmaxf(((gy + 1.0f) * (float)H - 1.0f) * 0.5f, 0.0f), (float)(H - 1));
            float x0f = floorf(x), y0f = floorf(y);
            float x1f = fminf(x0f + 1.0f, (float)(W - 1));
            float y1f = fminf(y0f + 1.0f, (float)(H - 1));
            float wx = x - x0f, wy = y - y0f;
            int x0i = (int)x0f, x1i = (int)x1f, y0i = (int)y0f, y1i = (int)y1f;
            int i00 = y0i * W + x0i, i01 = y0i * W + x1i;
            int i10 = y1i * W + x0i, i11 = y1i * W + x1i;
            float w00 = (1.0f - wx) * (1.0f - wy), w01 = wx * (1.0f - wy);
            float w10 = (1.0f - wx) * wy,          w11 = wx * wy;
            float uval = ub[i00] * w00 + ub[i01] * w01 + ub[i10] * w10 + ub[i11] * w11;
            const float* qp = qb;
            const float* rp = rb;
#pragma unroll 4
            for (int c = 0; c < C; c++) {
                float qv = qp[i00] * w00 + qp[i01] * w01 + qp[i10] * w10 + qp[i11] * w11;
                float rv = rp[i00] * w00 + rp[i01] * w01 + rp[i10] * w10 + rp[i11] * w11;
                float d = qv - rv;
                acc += uval * (d * d);
                qp += HW; rp += HW;
            }
        }
        float v = acc;
        for (int off = 32; off > 0; off >>= 1) v += __shfl_down(v, off, 64);
        if ((tid & 63) == 0) red[tid >> 6] = v;
        __syncthreads();
        if (tid == 0) {
            float s = 0.0f;
            for (int w = 0; w < 8; w++) s += red[w];
            float res = s / 500.0f;
            *resS = res;
            if (iter == 8) out[128 + b * NM + m] = res;
        }
        __syncthreads();
        if (tid < 6) {
            uint32_t fi = (uint32_t)((b * NM + m) * 6 + tid);
            float nz = jax_normal(iks.k0[iter], iks.k1[iter], fi, 3456u);
            stepS[tid] = (((-iks.damping[iter]) * (*resS)) * nz) * 0.01f;
        }
        __syncthreads();
        if (tid == 0) {
            float xi[6];
            for (int j = 0; j < 6; j++) xi[j] = stepS[j];
            float dT[12];
            se3_exp6(xi, dT);
            float Told[16];
            for (int k = 0; k < 16; k++) Told[k] = Tsh[k];
            float Tn[16];
            compose44(dT, Told, Tn);
            for (int k = 0; k < 16; k++) Tsh[k] = Tn[k];
        }
        __syncthreads();
    }
}

__global__ __launch_bounds__(512) void evolve_kernel_nchw(
    const float* __restrict__ T_pred, const float* __restrict__ geo,
    const float* __restrict__ Kmat,
    const float* __restrict__ q0, const float* __restrict__ q1, const float* __restrict__ q2,
    const float* __restrict__ r0, const float* __restrict__ r1, const float* __restrict__ r2,
    const float* __restrict__ u0, const float* __restrict__ u1, const float* __restrict__ u2,
    float* __restrict__ Tws, float* __restrict__ out,
    uint32_t hk0, uint32_t hk1, IterKeys iks) {
    const int bm = blockIdx.x;
    const int b = bm >> 4;
    const int m = bm & 15;
    const int tid = threadIdx.x;

    __shared__ float Tsh[16];
    __shared__ float geoS[NPTS * 3];
    __shared__ float red[8];
    __shared__ float resS;
    __shared__ float stepS[6];

    for (int i = tid; i < NPTS * 3; i += 512) geoS[i] = geo[b * NPTS * 3 + i];

    if (tid == 0) {
        float P[16];
        for (int k = 0; k < 16; k++) P[k] = T_pred[b * 16 + k];
        float Tn[16];
        make_hypothesis(m, P, hk0, hk1, Tn);
        for (int k = 0; k < 16; k++) Tsh[k] = Tn[k];
    }
    __syncthreads();

    float K00 = Kmat[b * 9 + 0], K02 = Kmat[b * 9 + 2];
    float K11 = Kmat[b * 9 + 4], K12 = Kmat[b * 9 + 5];

    run_level_nchw<128, 48, 64>(q0 + (size_t)b * 128 * 48 * 64, r0 + (size_t)b * 128 * 48 * 64,
                                u0 + (size_t)b * 48 * 64,
                                K00 * 0.25f, K11 * 0.25f, K02 * 0.25f, K12 * 0.25f,
                                geoS, Tsh, red, &resS, stepS, out, b, m, iks, 0, 2);
    run_level_nchw<64, 96, 128>(q1 + (size_t)b * 64 * 96 * 128, r1 + (size_t)b * 64 * 96 * 128,
                                u1 + (size_t)b * 96 * 128,
                                K00 * 0.5f, K11 * 0.5f, K02 * 0.5f, K12 * 0.5f,
                                geoS, Tsh, red, &resS, stepS, out, b, m, iks, 2, 3);
    run_level_nchw<32, 192, 256>(q2 + (size_t)b * 32 * 192 * 256, r2 + (size_t)b * 32 * 192 * 256,
                                 u2 + (size_t)b * 192 * 256,
                                 K00, K11, K02, K12,
                                 geoS, Tsh, red, &resS, stepS, out, b, m, iks, 5, 4);

    if (tid < 16) Tws[(size_t)bm * 16 + tid] = Tsh[tid];
}

// ---------------- Kernel 2: geodesic prior + argmin + T_best (f64 path) ----------------
__global__ __launch_bounds__(192) void finalize_kernel(
    const float* __restrict__ T_pred, const float* __restrict__ Tws,
    float* __restrict__ out, uint32_t hk0, uint32_t hk1) {
    const int b = blockIdx.x;
    const int tid = threadIdx.x;
    __shared__ double Pm[16];
    __shared__ double inv[12];
    __shared__ double totals[NM];
    __shared__ int bestm_sh;

    if (tid < 16) Pm[tid] = (double)T_pred[b * 16 + tid];
    __syncthreads();
    if (tid == 0) {
        for (int k = 0; k < 3; k++)
            for (int j = 0; j < 3; j++) inv[k * 4 + j] = Pm[j * 4 + k];
        for (int k = 0; k < 3; k++)
            inv[k * 4 + 3] = -(Pm[0 * 4 + k] * Pm[3] + Pm[1 * 4 + k] * Pm[7] + Pm[2 * 4 + k] * Pm[11]);
    }
    __syncthreads();

    double Tc[16];
    if (tid < NM) {
        double cost;
        if (tid < NM16) {
            for (int k = 0; k < 16; k++) Tc[k] = (double)Tws[(size_t)(b * NM16 + tid) * 16 + k];
            cost = (double)out[128 + b * NM + tid];
        } else {
            make_hypothesis_d(tid, Pm, hk0, hk1, Tc);
            cost = 0.0;
            out[128 + b * NM + tid] = 0.0f;
        }
        double Tr[12];
        for (int i = 0; i < 3; i++)
            for (int j = 0; j < 4; j++)
                Tr[i * 4 + j] = Tc[i * 4 + 0] * inv[0 + j] + Tc[i * 4 + 1] * inv[4 + j] +
                                Tc[i * 4 + 2] * inv[8 + j] + ((j == 3) ? Tc[i * 4 + 3] : 0.0);
        double cos_a = (Tr[0] + Tr[5] + Tr[10] - 1.0) * 0.5;
        cos_a = fmin(fmax(cos_a, -1.0 + 1e-7), 1.0 - 1e-7);
        double theta = acos(cos_a);
        double th = fmax(theta, 1e-8);
        double s2 = 2.0 * fmax(sin(th), 1e-8);
        double w0 = (Tr[2 * 4 + 1] - Tr[1 * 4 + 2]) / s2 * th;
        double w1 = (Tr[0 * 4 + 2] - Tr[2 * 4 + 0]) / s2 * th;
        double w2 = (Tr[1 * 4 + 0] - Tr[0 * 4 + 1]) / s2 * th;
        double t0 = Tr[3], t1 = Tr[7], t2 = Tr[11];
        double geod = sqrt(t0 * t0 + t1 * t1 + t2 * t2 + w0 * w0 + w1 * w1 + w2 * w2);
        totals[tid] = cost + geod;
    }
    __syncthreads();
    if (tid == 0) {
        int best = 0;
        double bv = totals[0];
        for (int mm = 1; mm < NM; mm++) {
            if (totals[mm] < bv) { bv = totals[mm]; best = mm; }
        }
        bestm_sh = best;
    }
    __syncthreads();
    if (tid == bestm_sh) {
        for (int k = 0; k < 16; k++) out[b * 16 + k] = (float)Tc[k];
    }
}

extern "C" void kernel_launch(void* const* d_in, const int* in_sizes, int n_in,
                              void* d_out, int out_size, void* d_ws, size_t ws_size,
                              hipStream_t stream) {
    (void)in_sizes; (void)n_in; (void)out_size;
    const float* T_pred = (const float*)d_in[0];
    const float* geo    = (const float*)d_in[1];
    const float* K      = (const float*)d_in[2];
    const float* q0 = (const float*)d_in[3];
    const float* q1 = (const float*)d_in[4];
    const float* q2 = (const float*)d_in[5];
    const float* r0 = (const float*)d_in[6];
    const float* r1 = (const float*)d_in[7];
    const float* r2 = (const float*)d_in[8];
    const float* u0 = (const float*)d_in[9];
    const float* u1 = (const float*)d_in[10];
    const float* u2 = (const float*)d_in[11];
    float* out = (float*)d_out;   // [0:128] T_best (8,4,4); [128:1280] costs (8,144)

    // workspace: Tws (2048 f) | G0 | G1 | G2   (GP floats per pixel)
    float* Tws = (float*)d_ws;
    const size_t nG0 = (size_t)NB * 48 * 64 * GP;     //   393,216
    const size_t nG1 = (size_t)NB * 96 * 128 * GP;    // 1,572,864
    const size_t nG2 = (size_t)NB * 192 * 256 * GP;   // 6,291,456
    float* G0 = Tws + 2048;
    float* G1 = G0 + nG0;
    float* G2 = G1 + nG1;
    const size_t need = (2048 + nG0 + nG1 + nG2) * sizeof(float);   // ~33 MB

    // host-side key derivation (pure integer math; graph-capture safe)
    uint32_t hk0, hk1;
    threefry2x32(0u, 42u, 0u, 0u, hk0, hk1);  // fold_in(key(42), 0)
    IterKeys iks;
    const int seeds[9] = {100, 101, 110, 111, 112, 120, 121, 122, 123};
    const float damp[9] = {0.001f, 0.001f, 0.0005f, 0.0005f, 0.0005f,
                           0.00025f, 0.00025f, 0.00025f, 0.00025f};
    for (int i = 0; i < 9; i++) {
        threefry2x32(0u, 42u, 0u, (uint32_t)seeds[i], iks.k0[i], iks.k1[i]);
        iks.damping[i] = damp[i];
    }

    if (ws_size >= need) {
        gram_kernel<128, 48, 64, 1><<<dim3(12, NB), dim3(256), 0, stream>>>(q0, r0, G0);
        gram_kernel<64, 96, 128, 2><<<dim3(24, NB), dim3(256), 0, stream>>>(q1, r1, G1);
        gram_kernel<32, 192, 256, 4><<<dim3(48, NB), dim3(256), 0, stream>>>(q2, r2, G2);
        evolve_kernel_gram<<<dim3(NB * NM16), dim3(512), 0, stream>>>(
            T_pred, geo, K, G0, G1, G2, u0, u1, u2, Tws, out, hk0, hk1, iks);
    } else {
        evolve_kernel_nchw<<<dim3(NB * NM16), dim3(512), 0, stream>>>(
            T_pred, geo, K, q0, q1, q2, r0, r1, r2, u0, u1, u2, Tws, out, hk0, hk1, iks);
    }
    finalize_kernel<<<dim3(NB), dim3(192), 0, stream>>>(T_pred, Tws, out, hk0, hk1);
}

// Round 7
// 272.938 us; speedup vs baseline: 1.6975x; 1.4392x over previous
//
#include <hip/hip_runtime.h>
#include <stdint.h>
#include <math.h>

#define JAX_PARTITIONABLE 1

#define NB 8
#define NM 144
#define NM16 16
#define NPTS 500
#define GP 16   // floats per pixel record: 10 Gram + 4 u-taps + 2 pad = one 64B line

// ---------------- Threefry-2x32 (JAX-exact) ----------------
__host__ __device__ __forceinline__ uint32_t rotl32(uint32_t x, int r) {
    return (x << r) | (x >> (32 - r));
}

__host__ __device__ inline void threefry2x32(uint32_t k0, uint32_t k1,
                                             uint32_t x0, uint32_t x1,
                                             uint32_t& o0, uint32_t& o1) {
    uint32_t ks2 = k0 ^ k1 ^ 0x1BD11BDAu;
    x0 += k0; x1 += k1;
    const int RA[4] = {13, 15, 26, 6};
    const int RB[4] = {17, 29, 16, 24};
#define R4(ROT) { x0 += x1; x1 = rotl32(x1, ROT[0]); x1 ^= x0; \
                  x0 += x1; x1 = rotl32(x1, ROT[1]); x1 ^= x0; \
                  x0 += x1; x1 = rotl32(x1, ROT[2]); x1 ^= x0; \
                  x0 += x1; x1 = rotl32(x1, ROT[3]); x1 ^= x0; }
    R4(RA); x0 += k1;  x1 += ks2 + 1u;
    R4(RB); x0 += ks2; x1 += k0 + 2u;
    R4(RA); x0 += k0;  x1 += k1 + 3u;
    R4(RB); x0 += k1;  x1 += ks2 + 4u;
    R4(RA); x0 += ks2; x1 += k0 + 5u;
#undef R4
    o0 = x0; o1 = x1;
}

// XLA f32 erf_inv (Giles polynomial pair)
__device__ __forceinline__ float erfinv32(float x) {
    float w = -log1pf(-x * x);
    float p;
    if (w < 5.0f) {
        w = w - 2.5f;
        p = 2.81022636e-08f;
        p = fmaf(p, w, 3.43273939e-07f);
        p = fmaf(p, w, -3.5233877e-06f);
        p = fmaf(p, w, -4.39150654e-06f);
        p = fmaf(p, w, 0.00021858087f);
        p = fmaf(p, w, -0.00125372503f);
        p = fmaf(p, w, -0.00417768164f);
        p = fmaf(p, w, 0.246640727f);
        p = fmaf(p, w, 1.50140941f);
    } else {
        w = sqrtf(w) - 3.0f;
        p = -0.000200214257f;
        p = fmaf(p, w, 0.000100950558f);
        p = fmaf(p, w, 0.00134934322f);
        p = fmaf(p, w, -0.00367342844f);
        p = fmaf(p, w, 0.00573950773f);
        p = fmaf(p, w, -0.0076224613f);
        p = fmaf(p, w, 0.00943887047f);
        p = fmaf(p, w, 1.00167406f);
        p = fmaf(p, w, 2.83297682f);
    }
    return p * x;
}

// jax.random.normal element at flat index idx (partitionable: bits = o0^o1).
__device__ __forceinline__ float jax_normal(uint32_t k0, uint32_t k1,
                                            uint32_t idx, uint32_t half) {
    uint32_t o0, o1, bits;
#if JAX_PARTITIONABLE
    threefry2x32(k0, k1, 0u, idx, o0, o1);
    bits = o0 ^ o1;
#else
    if (idx < half) { threefry2x32(k0, k1, idx, idx + half, o0, o1); bits = o0; }
    else            { threefry2x32(k0, k1, idx - half, idx, o0, o1); bits = o1; }
#endif
    uint32_t fb = (bits >> 9) | 0x3F800000u;
    float f = __uint_as_float(fb) - 1.0f;           // [0,1)
    const float lo = -0.99999994f;                  // nextafter(-1,0) f32
    float u = f * (1.0f - lo) + lo;                 // (1.0f - lo) == 2.0f
    u = fmaxf(lo, u);
    return 1.4142135623730951f * erfinv32(u);
}

// ---------------- SE(3) helpers, f32 (evolve path) ----------------
__device__ inline void se3_exp6(const float xi[6], float T[12]) {
    float tx = xi[0], ty = xi[1], tz = xi[2];
    float wx = xi[3], wy = xi[4], wz = xi[5];
    float nrm = sqrtf(wx * wx + wy * wy + wz * wz);
    float theta = fmaxf(nrm, 1e-8f);
    float kx = wx / theta, ky = wy / theta, kz = wz / theta;
    float K[9] = {0.0f, -kz, ky, kz, 0.0f, -kx, -ky, kx, 0.0f};
    float st = sinf(theta);
    float ct = 1.0f - cosf(theta);
    float KK[9];
    for (int i = 0; i < 3; i++)
        for (int j = 0; j < 3; j++)
            KK[i * 3 + j] = K[i * 3 + 0] * K[0 + j] + K[i * 3 + 1] * K[3 + j] + K[i * 3 + 2] * K[6 + j];
    float a = ct / theta;
    float bb = 1.0f - st / theta;
    float R[9], V[9];
    for (int i = 0; i < 3; i++)
        for (int j = 0; j < 3; j++) {
            float e = (i == j) ? 1.0f : 0.0f;
            R[i * 3 + j] = e + st * K[i * 3 + j] + ct * KK[i * 3 + j];
            V[i * 3 + j] = e + a * K[i * 3 + j] + bb * KK[i * 3 + j];
        }
    float t0 = V[0] * tx + V[1] * ty + V[2] * tz;
    float t1 = V[3] * tx + V[4] * ty + V[5] * tz;
    float t2 = V[6] * tx + V[7] * ty + V[8] * tz;
    T[0] = R[0]; T[1] = R[1]; T[2] = R[2];  T[3] = t0;
    T[4] = R[3]; T[5] = R[4]; T[6] = R[5];  T[7] = t1;
    T[8] = R[6]; T[9] = R[7]; T[10] = R[8]; T[11] = t2;
}

__device__ inline void compose44(const float dT[12], const float P[16], float Tn[16]) {
    for (int i = 0; i < 3; i++)
        for (int j = 0; j < 4; j++)
            Tn[i * 4 + j] = dT[i * 4 + 0] * P[0 + j] + dT[i * 4 + 1] * P[4 + j] +
                            dT[i * 4 + 2] * P[8 + j] + dT[i * 4 + 3] * P[12 + j];
    Tn[12] = 0.0f; Tn[13] = 0.0f; Tn[14] = 0.0f; Tn[15] = 1.0f;
}

__device__ inline void make_hypothesis(int m, const float* P, uint32_t hk0, uint32_t hk1,
                                       float Tn[16]) {
    float tn[3];
    for (int c = 0; c < 3; c++)
        tn[c] = jax_normal(hk0, hk1, (uint32_t)(m * 3 + c), 216u);
    int gi = m / 12, gj = m % 12;
    const float d2r = (float)(M_PI / 180.0);
    float xi[6] = {tn[0], tn[1], tn[2], 0.0f,
                   (float)(2 * gi - 11) * d2r, (float)(2 * gj - 11) * d2r};
    float dT[12];
    se3_exp6(xi, dT);
    compose44(dT, P, Tn);
}

// ---------------- SE(3) helpers, f64 (finalize path) ----------------
__device__ inline void se3_exp6d(const double xi[6], double T[12]) {
    double tx = xi[0], ty = xi[1], tz = xi[2];
    double wx = xi[3], wy = xi[4], wz = xi[5];
    double nrm = sqrt(wx * wx + wy * wy + wz * wz);
    double theta = fmax(nrm, 1e-8);
    double kx = wx / theta, ky = wy / theta, kz = wz / theta;
    double K[9] = {0.0, -kz, ky, kz, 0.0, -kx, -ky, kx, 0.0};
    double st = sin(theta);
    double ct = 1.0 - cos(theta);
    double KK[9];
    for (int i = 0; i < 3; i++)
        for (int j = 0; j < 3; j++)
            KK[i * 3 + j] = K[i * 3 + 0] * K[0 + j] + K[i * 3 + 1] * K[3 + j] + K[i * 3 + 2] * K[6 + j];
    double a = ct / theta;
    double bb = 1.0 - st / theta;
    double R[9], V[9];
    for (int i = 0; i < 3; i++)
        for (int j = 0; j < 3; j++) {
            double e = (i == j) ? 1.0 : 0.0;
            R[i * 3 + j] = e + st * K[i * 3 + j] + ct * KK[i * 3 + j];
            V[i * 3 + j] = e + a * K[i * 3 + j] + bb * KK[i * 3 + j];
        }
    double t0 = V[0] * tx + V[1] * ty + V[2] * tz;
    double t1 = V[3] * tx + V[4] * ty + V[5] * tz;
    double t2 = V[6] * tx + V[7] * ty + V[8] * tz;
    T[0] = R[0]; T[1] = R[1]; T[2] = R[2];  T[3] = t0;
    T[4] = R[3]; T[5] = R[4]; T[6] = R[5];  T[7] = t1;
    T[8] = R[6]; T[9] = R[7]; T[10] = R[8]; T[11] = t2;
}

__device__ inline void compose44d(const double dT[12], const double P[16], double Tn[16]) {
    for (int i = 0; i < 3; i++)
        for (int j = 0; j < 4; j++)
            Tn[i * 4 + j] = dT[i * 4 + 0] * P[0 + j] + dT[i * 4 + 1] * P[4 + j] +
                            dT[i * 4 + 2] * P[8 + j] + dT[i * 4 + 3] * P[12 + j];
    Tn[12] = 0.0; Tn[13] = 0.0; Tn[14] = 0.0; Tn[15] = 1.0;
}

__device__ inline void make_hypothesis_d(int m, const double* P, uint32_t hk0, uint32_t hk1,
                                         double Tn[16]) {
    float tn[3];
    for (int c = 0; c < 3; c++)
        tn[c] = jax_normal(hk0, hk1, (uint32_t)(m * 3 + c), 216u);
    int gi = m / 12, gj = m % 12;
    const float d2r = (float)(M_PI / 180.0);
    float pf = (float)(2 * gi - 11) * d2r;
    float yf = (float)(2 * gj - 11) * d2r;
    double xi[6] = {(double)tn[0], (double)tn[1], (double)tn[2], 0.0,
                    (double)pf, (double)yf};
    double dT[12];
    se3_exp6d(xi, dT);
    compose44d(dT, P, Tn);
}

struct IterKeys { uint32_t k0[9]; uint32_t k1[9]; float damping[9]; };

// ---------------- Fused Gram builder (all 3 levels, one launch) ----------------
// Thread = (pixel, channel-group of 32). Private 10-term Gram accumulation with
// direct global reads (no per-channel barriers); LDS partial-reduce when GRP>1.
// Record: [M00,M01,M02,M03 | M11,M12,M13,M22 | M23,M33,u00,u01 | u10,u11,0,0]
template <int C, int H, int W, int PX, int GRP>
__device__ void gram_body(const float* __restrict__ q, const float* __restrict__ r,
                          const float* __restrict__ u, float* __restrict__ G,
                          float* part, int blk) {
    constexpr int HW = H * W;
    constexpr int TPB = HW / PX;       // pixel tiles per batch
    constexpr int CPG = C / GRP;       // channels per group (=32)
    const int b = blk / TPB;
    const int tile = blk % TPB;
    const int tid = threadIdx.x;
    const int g = tid / PX;
    const int p = tid % PX;
    const int px = tile * PX + p;
    const int y = px / W, x = px % W;
    const int x1 = (x + 1 < W) ? x + 1 : W - 1;
    const int y1 = (y + 1 < H) ? y + 1 : H - 1;
    const int i00 = y * W + x,  i01 = y * W + x1;
    const int i10 = y1 * W + x, i11 = y1 * W + x1;

    const size_t cb = ((size_t)b * C + g * CPG) * HW;
    const float* qp = q + cb;
    const float* rp = r + cb;
    float acc[10];
#pragma unroll
    for (int i = 0; i < 10; i++) acc[i] = 0.0f;
#pragma unroll 4
    for (int c = 0; c < CPG; c++) {
        float d00 = qp[i00] - rp[i00];
        float d01 = qp[i01] - rp[i01];
        float d10 = qp[i10] - rp[i10];
        float d11 = qp[i11] - rp[i11];
        acc[0] = fmaf(d00, d00, acc[0]);
        acc[1] = fmaf(d00, d01, acc[1]);
        acc[2] = fmaf(d00, d10, acc[2]);
        acc[3] = fmaf(d00, d11, acc[3]);
        acc[4] = fmaf(d01, d01, acc[4]);
        acc[5] = fmaf(d01, d10, acc[5]);
        acc[6] = fmaf(d01, d11, acc[6]);
        acc[7] = fmaf(d10, d10, acc[7]);
        acc[8] = fmaf(d10, d11, acc[8]);
        acc[9] = fmaf(d11, d11, acc[9]);
        qp += HW; rp += HW;
    }
    if (GRP > 1) {
        // part layout [g][i][p]: conflict-free writes and reads
#pragma unroll
        for (int i = 0; i < 10; i++) part[(g * 10 + i) * PX + p] = acc[i];
        __syncthreads();
        if (tid < PX) {
#pragma unroll
            for (int i = 0; i < 10; i++) {
                float s = part[i * PX + p];
                for (int gg = 1; gg < GRP; gg++) s += part[(gg * 10 + i) * PX + p];
                acc[i] = s;
            }
        }
    }
    if (tid < PX) {
        const size_t ub = (size_t)b * HW;
        float u00 = u[ub + i00], u01 = u[ub + i01];
        float u10 = u[ub + i10], u11 = u[ub + i11];
        size_t base = ((size_t)b * HW + px) * GP;
        float4 g0 = {acc[0], acc[1], acc[2], acc[3]};
        float4 g1 = {acc[4], acc[5], acc[6], acc[7]};
        float4 g2 = {acc[8], acc[9], u00, u01};
        float4 g3 = {u10, u11, 0.0f, 0.0f};
        *(float4*)(G + base + 0)  = g0;
        *(float4*)(G + base + 4)  = g1;
        *(float4*)(G + base + 8)  = g2;
        *(float4*)(G + base + 12) = g3;
    }
}

#define NBLK0 384    // 8 * (48*64/64)   groups x4
#define NBLK1 768    // 8 * (96*128/128) groups x2
#define NBLK2 1536   // 8 * (192*256/256)

__global__ __launch_bounds__(256) void gram_fused_kernel(
    const float* __restrict__ q0, const float* __restrict__ r0, const float* __restrict__ u0,
    float* __restrict__ G0,
    const float* __restrict__ q1, const float* __restrict__ r1, const float* __restrict__ u1,
    float* __restrict__ G1,
    const float* __restrict__ q2, const float* __restrict__ r2, const float* __restrict__ u2,
    float* __restrict__ G2) {
    __shared__ float part[2560];   // max(GRP*10*PX) = 2560 floats
    const int blk = blockIdx.x;
    if (blk < NBLK0)
        gram_body<128, 48, 64, 64, 4>(q0, r0, u0, G0, part, blk);
    else if (blk < NBLK0 + NBLK1)
        gram_body<64, 96, 128, 128, 2>(q1, r1, u1, G1, part, blk - NBLK0);
    else
        gram_body<32, 192, 256, 256, 1>(q2, r2, u2, G2, part, blk - NBLK0 - NBLK1);
}

// ---------------- Kernel 1 (Gram): per-(b,m) full 9-iteration LM ----------------
template <int H, int W>
__device__ void run_level_gram(const float* __restrict__ Gb,
                               float fx, float fy, float cx, float cy,
                               const float* geoS, float* Tsh, float* red, float* resS,
                               float* stepS, float* out, int b, int m,
                               const IterKeys& iks, int firstIter, int niter) {
    const int tid = threadIdx.x;
    for (int it = 0; it < niter; it++) {
        const int iter = firstIter + it;
        float acc = 0.0f;
        if (tid < NPTS) {
            float px = geoS[tid * 3], py = geoS[tid * 3 + 1], pz = geoS[tid * 3 + 2];
            float X = Tsh[0] * px + Tsh[1] * py + Tsh[2]  * pz + Tsh[3];
            float Y = Tsh[4] * px + Tsh[5] * py + Tsh[6]  * pz + Tsh[7];
            float Z = Tsh[8] * px + Tsh[9] * py + Tsh[10] * pz + Tsh[11];
            float z = fmaxf(Z, 1e-6f);
            float uu = fx * (X / z) + cx;
            float vv = fy * (Y / z) + cy;
            float gx = 2.0f * uu / (float)(W - 1) - 1.0f;
            float gy = 2.0f * vv / (float)(H - 1) - 1.0f;
            float x = fminf(fmaxf(((gx + 1.0f) * (float)W - 1.0f) * 0.5f, 0.0f), (float)(W - 1));
            float y = fminf(fmaxf(((gy + 1.0f) * (float)H - 1.0f) * 0.5f, 0.0f), (float)(H - 1));
            float x0f = floorf(x), y0f = floorf(y);
            float wx = x - x0f, wy = y - y0f;
            int x0i = (int)x0f, y0i = (int)y0f;
            int i00 = y0i * W + x0i;
            float w00 = (1.0f - wx) * (1.0f - wy), w01 = wx * (1.0f - wy);
            float w10 = (1.0f - wx) * wy,          w11 = wx * wy;
            const float* Gp = Gb + (size_t)i00 * GP;
            float4 g0 = *(const float4*)(Gp + 0);
            float4 g1 = *(const float4*)(Gp + 4);
            float4 g2 = *(const float4*)(Gp + 8);
            float4 g3 = *(const float4*)(Gp + 12);
            float uval = w00 * g2.z + w01 * g2.w + w10 * g3.x + w11 * g3.y;
            float val = w00 * w00 * g0.x + w01 * w01 * g1.x +
                        w10 * w10 * g1.w + w11 * w11 * g2.y +
                        2.0f * (w00 * w01 * g0.y + w00 * w10 * g0.z + w00 * w11 * g0.w +
                                w01 * w10 * g1.y + w01 * w11 * g1.z + w10 * w11 * g2.x);
            acc = uval * val;
        }
        // block reduction (8 waves)
        float v = acc;
        for (int off = 32; off > 0; off >>= 1) v += __shfl_down(v, off, 64);
        if ((tid & 63) == 0) red[tid >> 6] = v;
        __syncthreads();
        if (tid == 0) {
            float s = 0.0f;
            for (int w = 0; w < 8; w++) s += red[w];
            float res = s / 500.0f;
            *resS = res;
            if (iter == 8) out[128 + b * NM + m] = res;
        }
        __syncthreads();
        if (tid < 6) {
            uint32_t fi = (uint32_t)((b * NM + m) * 6 + tid);
            float nz = jax_normal(iks.k0[iter], iks.k1[iter], fi, 3456u);
            stepS[tid] = (((-iks.damping[iter]) * (*resS)) * nz) * 0.01f;
        }
        __syncthreads();
        if (tid == 0) {
            float xi[6];
            for (int j = 0; j < 6; j++) xi[j] = stepS[j];
            float dT[12];
            se3_exp6(xi, dT);
            float Told[16];
            for (int k = 0; k < 16; k++) Told[k] = Tsh[k];
            float Tn[16];
            compose44(dT, Told, Tn);
            for (int k = 0; k < 16; k++) Tsh[k] = Tn[k];
        }
        __syncthreads();
    }
}

__global__ __launch_bounds__(512) void evolve_kernel_gram(
    const float* __restrict__ T_pred, const float* __restrict__ geo,
    const float* __restrict__ Kmat,
    const float* __restrict__ G0, const float* __restrict__ G1, const float* __restrict__ G2,
    float* __restrict__ Tws, float* __restrict__ out,
    uint32_t hk0, uint32_t hk1, IterKeys iks) {
    const int bm = blockIdx.x;
    // XCD swizzle: b = bm%8 keeps one batch's G slice on one XCD's L2.
    const int b = bm & 7;
    const int m = bm >> 3;
    const int tid = threadIdx.x;

    __shared__ float Tsh[16];
    __shared__ float geoS[NPTS * 3];
    __shared__ float red[8];
    __shared__ float resS;
    __shared__ float stepS[6];

    for (int i = tid; i < NPTS * 3; i += 512) geoS[i] = geo[b * NPTS * 3 + i];

    if (tid == 0) {
        float P[16];
        for (int k = 0; k < 16; k++) P[k] = T_pred[b * 16 + k];
        float Tn[16];
        make_hypothesis(m, P, hk0, hk1, Tn);
        for (int k = 0; k < 16; k++) Tsh[k] = Tn[k];
    }
    __syncthreads();

    float K00 = Kmat[b * 9 + 0], K02 = Kmat[b * 9 + 2];
    float K11 = Kmat[b * 9 + 4], K12 = Kmat[b * 9 + 5];

    run_level_gram<48, 64>(G0 + (size_t)b * 48 * 64 * GP,
                           K00 * 0.25f, K11 * 0.25f, K02 * 0.25f, K12 * 0.25f,
                           geoS, Tsh, red, &resS, stepS, out, b, m, iks, 0, 2);
    run_level_gram<96, 128>(G1 + (size_t)b * 96 * 128 * GP,
                            K00 * 0.5f, K11 * 0.5f, K02 * 0.5f, K12 * 0.5f,
                            geoS, Tsh, red, &resS, stepS, out, b, m, iks, 2, 3);
    run_level_gram<192, 256>(G2 + (size_t)b * 192 * 256 * GP,
                             K00, K11, K02, K12,
                             geoS, Tsh, red, &resS, stepS, out, b, m, iks, 5, 4);

    if (tid < 16) Tws[(size_t)(b * NM16 + m) * 16 + tid] = Tsh[tid];
}

// ---------------- Fallback (NCHW gather, proven-correct) ----------------
template <int C, int H, int W>
__device__ void run_level_nchw(const float* __restrict__ qb, const float* __restrict__ rb,
                               const float* __restrict__ ub,
                               float fx, float fy, float cx, float cy,
                               const float* geoS, float* Tsh, float* red, float* resS,
                               float* stepS, float* out, int b, int m,
                               const IterKeys& iks, int firstIter, int niter) {
    const int tid = threadIdx.x;
    const int HW = H * W;
    for (int it = 0; it < niter; it++) {
        const int iter = firstIter + it;
        float acc = 0.0f;
        if (tid < NPTS) {
            float px = geoS[tid * 3], py = geoS[tid * 3 + 1], pz = geoS[tid * 3 + 2];
            float X = Tsh[0] * px + Tsh[1] * py + Tsh[2]  * pz + Tsh[3];
            float Y = Tsh[4] * px + Tsh[5] * py + Tsh[6]  * pz + Tsh[7];
            float Z = Tsh[8] * px + Tsh[9] * py + Tsh[10] * pz + Tsh[11];
            float z = fmaxf(Z, 1e-6f);
            float uu = fx * (X / z) + cx;
            float vv = fy * (Y / z) + cy;
            float gx = 2.0f * uu / (float)(W - 1) - 1.0f;
            float gy = 2.0f * vv / (float)(H - 1) - 1.0f;
            float x = fminf(fmaxf(((gx + 1.0f) * (float)W - 1.0f) * 0.5f, 0.0f), (float)(W - 1));
            float y = fminf(fmaxf(((gy + 1.0f) * (float)H - 1.0f) * 0.5f, 0.0f), (float)(H - 1));
            float x0f = floorf(x), y0f = floorf(y);
            float x1f = fminf(x0f + 1.0f, (float)(W - 1));
            float y1f = fminf(y0f + 1.0f, (float)(H - 1));
            float wx = x - x0f, wy = y - y0f;
            int x0i = (int)x0f, x1i = (int)x1f, y0i = (int)y0f, y1i = (int)y1f;
            int i00 = y0i * W + x0i, i01 = y0i * W + x1i;
            int i10 = y1i * W + x0i, i11 = y1i * W + x1i;
            float w00 = (1.0f - wx) * (1.0f - wy), w01 = wx * (1.0f - wy);
            float w10 = (1.0f - wx) * wy,          w11 = wx * wy;
            float uval = ub[i00] * w00 + ub[i01] * w01 + ub[i10] * w10 + ub[i11] * w11;
            const float* qp = qb;
            const float* rp = rb;
#pragma unroll 4
            for (int c = 0; c < C; c++) {
                float qv = qp[i00] * w00 + qp[i01] * w01 + qp[i10] * w10 + qp[i11] * w11;
                float rv = rp[i00] * w00 + rp[i01] * w01 + rp[i10] * w10 + rp[i11] * w11;
                float d = qv - rv;
                acc += uval * (d * d);
                qp += HW; rp += HW;
            }
        }
        float v = acc;
        for (int off = 32; off > 0; off >>= 1) v += __shfl_down(v, off, 64);
        if ((tid & 63) == 0) red[tid >> 6] = v;
        __syncthreads();
        if (tid == 0) {
            float s = 0.0f;
            for (int w = 0; w < 8; w++) s += red[w];
            float res = s / 500.0f;
            *resS = res;
            if (iter == 8) out[128 + b * NM + m] = res;
        }
        __syncthreads();
        if (tid < 6) {
            uint32_t fi = (uint32_t)((b * NM + m) * 6 + tid);
            float nz = jax_normal(iks.k0[iter], iks.k1[iter], fi, 3456u);
            stepS[tid] = (((-iks.damping[iter]) * (*resS)) * nz) * 0.01f;
        }
        __syncthreads();
        if (tid == 0) {
            float xi[6];
            for (int j = 0; j < 6; j++) xi[j] = stepS[j];
            float dT[12];
            se3_exp6(xi, dT);
            float Told[16];
            for (int k = 0; k < 16; k++) Told[k] = Tsh[k];
            float Tn[16];
            compose44(dT, Told, Tn);
            for (int k = 0; k < 16; k++) Tsh[k] = Tn[k];
        }
        __syncthreads();
    }
}

__global__ __launch_bounds__(512) void evolve_kernel_nchw(
    const float* __restrict__ T_pred, const float* __restrict__ geo,
    const float* __restrict__ Kmat,
    const float* __restrict__ q0, const float* __restrict__ q1, const float* __restrict__ q2,
    const float* __restrict__ r0, const float* __restrict__ r1, const float* __restrict__ r2,
    const float* __restrict__ u0, const float* __restrict__ u1, const float* __restrict__ u2,
    float* __restrict__ Tws, float* __restrict__ out,
    uint32_t hk0, uint32_t hk1, IterKeys iks) {
    const int bm = blockIdx.x;
    const int b = bm >> 4;
    const int m = bm & 15;
    const int tid = threadIdx.x;

    __shared__ float Tsh[16];
    __shared__ float geoS[NPTS * 3];
    __shared__ float red[8];
    __shared__ float resS;
    __shared__ float stepS[6];

    for (int i = tid; i < NPTS * 3; i += 512) geoS[i] = geo[b * NPTS * 3 + i];

    if (tid == 0) {
        float P[16];
        for (int k = 0; k < 16; k++) P[k] = T_pred[b * 16 + k];
        float Tn[16];
        make_hypothesis(m, P, hk0, hk1, Tn);
        for (int k = 0; k < 16; k++) Tsh[k] = Tn[k];
    }
    __syncthreads();

    float K00 = Kmat[b * 9 + 0], K02 = Kmat[b * 9 + 2];
    float K11 = Kmat[b * 9 + 4], K12 = Kmat[b * 9 + 5];

    run_level_nchw<128, 48, 64>(q0 + (size_t)b * 128 * 48 * 64, r0 + (size_t)b * 128 * 48 * 64,
                                u0 + (size_t)b * 48 * 64,
                                K00 * 0.25f, K11 * 0.25f, K02 * 0.25f, K12 * 0.25f,
                                geoS, Tsh, red, &resS, stepS, out, b, m, iks, 0, 2);
    run_level_nchw<64, 96, 128>(q1 + (size_t)b * 64 * 96 * 128, r1 + (size_t)b * 64 * 96 * 128,
                                u1 + (size_t)b * 96 * 128,
                                K00 * 0.5f, K11 * 0.5f, K02 * 0.5f, K12 * 0.5f,
                                geoS, Tsh, red, &resS, stepS, out, b, m, iks, 2, 3);
    run_level_nchw<32, 192, 256>(q2 + (size_t)b * 32 * 192 * 256, r2 + (size_t)b * 32 * 192 * 256,
                                 u2 + (size_t)b * 192 * 256,
                                 K00, K11, K02, K12,
                                 geoS, Tsh, red, &resS, stepS, out, b, m, iks, 5, 4);

    if (tid < 16) Tws[(size_t)bm * 16 + tid] = Tsh[tid];
}

// ---------------- Kernel 2: geodesic prior + argmin + T_best (f64 path) ----------------
__global__ __launch_bounds__(192) void finalize_kernel(
    const float* __restrict__ T_pred, const float* __restrict__ Tws,
    float* __restrict__ out, uint32_t hk0, uint32_t hk1) {
    const int b = blockIdx.x;
    const int tid = threadIdx.x;
    __shared__ double Pm[16];
    __shared__ double inv[12];
    __shared__ double totals[NM];
    __shared__ int bestm_sh;

    if (tid < 16) Pm[tid] = (double)T_pred[b * 16 + tid];
    __syncthreads();
    if (tid == 0) {
        for (int k = 0; k < 3; k++)
            for (int j = 0; j < 3; j++) inv[k * 4 + j] = Pm[j * 4 + k];
        for (int k = 0; k < 3; k++)
            inv[k * 4 + 3] = -(Pm[0 * 4 + k] * Pm[3] + Pm[1 * 4 + k] * Pm[7] + Pm[2 * 4 + k] * Pm[11]);
    }
    __syncthreads();

    double Tc[16];
    if (tid < NM) {
        double cost;
        if (tid < NM16) {
            for (int k = 0; k < 16; k++) Tc[k] = (double)Tws[(size_t)(b * NM16 + tid) * 16 + k];
            cost = (double)out[128 + b * NM + tid];
        } else {
            make_hypothesis_d(tid, Pm, hk0, hk1, Tc);
            cost = 0.0;
            out[128 + b * NM + tid] = 0.0f;
        }
        double Tr[12];
        for (int i = 0; i < 3; i++)
            for (int j = 0; j < 4; j++)
                Tr[i * 4 + j] = Tc[i * 4 + 0] * inv[0 + j] + Tc[i * 4 + 1] * inv[4 + j] +
                                Tc[i * 4 + 2] * inv[8 + j] + ((j == 3) ? Tc[i * 4 + 3] : 0.0);
        double cos_a = (Tr[0] + Tr[5] + Tr[10] - 1.0) * 0.5;
        cos_a = fmin(fmax(cos_a, -1.0 + 1e-7), 1.0 - 1e-7);
        double theta = acos(cos_a);
        double th = fmax(theta, 1e-8);
        double s2 = 2.0 * fmax(sin(th), 1e-8);
        double w0 = (Tr[2 * 4 + 1] - Tr[1 * 4 + 2]) / s2 * th;
        double w1 = (Tr[0 * 4 + 2] - Tr[2 * 4 + 0]) / s2 * th;
        double w2 = (Tr[1 * 4 + 0] - Tr[0 * 4 + 1]) / s2 * th;
        double t0 = Tr[3], t1 = Tr[7], t2 = Tr[11];
        double geod = sqrt(t0 * t0 + t1 * t1 + t2 * t2 + w0 * w0 + w1 * w1 + w2 * w2);
        totals[tid] = cost + geod;
    }
    __syncthreads();
    if (tid == 0) {
        int best = 0;
        double bv = totals[0];
        for (int mm = 1; mm < NM; mm++) {
            if (totals[mm] < bv) { bv = totals[mm]; best = mm; }
        }
        bestm_sh = best;
    }
    __syncthreads();
    if (tid == bestm_sh) {
        for (int k = 0; k < 16; k++) out[b * 16 + k] = (float)Tc[k];
    }
}

extern "C" void kernel_launch(void* const* d_in, const int* in_sizes, int n_in,
                              void* d_out, int out_size, void* d_ws, size_t ws_size,
                              hipStream_t stream) {
    (void)in_sizes; (void)n_in; (void)out_size;
    const float* T_pred = (const float*)d_in[0];
    const float* geo    = (const float*)d_in[1];
    const float* K      = (const float*)d_in[2];
    const float* q0 = (const float*)d_in[3];
    const float* q1 = (const float*)d_in[4];
    const float* q2 = (const float*)d_in[5];
    const float* r0 = (const float*)d_in[6];
    const float* r1 = (const float*)d_in[7];
    const float* r2 = (const float*)d_in[8];
    const float* u0 = (const float*)d_in[9];
    const float* u1 = (const float*)d_in[10];
    const float* u2 = (const float*)d_in[11];
    float* out = (float*)d_out;   // [0:128] T_best (8,4,4); [128:1280] costs (8,144)

    // workspace: Tws (2048 f) | G0 | G1 | G2   (GP floats per pixel)
    float* Tws = (float*)d_ws;
    const size_t nG0 = (size_t)NB * 48 * 64 * GP;     //   393,216
    const size_t nG1 = (size_t)NB * 96 * 128 * GP;    // 1,572,864
    const size_t nG2 = (size_t)NB * 192 * 256 * GP;   // 6,291,456
    float* G0 = Tws + 2048;
    float* G1 = G0 + nG0;
    float* G2 = G1 + nG1;
    const size_t need = (2048 + nG0 + nG1 + nG2) * sizeof(float);   // ~33 MB

    // host-side key derivation (pure integer math; graph-capture safe)
    uint32_t hk0, hk1;
    threefry2x32(0u, 42u, 0u, 0u, hk0, hk1);  // fold_in(key(42), 0)
    IterKeys iks;
    const int seeds[9] = {100, 101, 110, 111, 112, 120, 121, 122, 123};
    const float damp[9] = {0.001f, 0.001f, 0.0005f, 0.0005f, 0.0005f,
                           0.00025f, 0.00025f, 0.00025f, 0.00025f};
    for (int i = 0; i < 9; i++) {
        threefry2x32(0u, 42u, 0u, (uint32_t)seeds[i], iks.k0[i], iks.k1[i]);
        iks.damping[i] = damp[i];
    }

    if (ws_size >= need) {
        gram_fused_kernel<<<dim3(NBLK0 + NBLK1 + NBLK2), dim3(256), 0, stream>>>(
            q0, r0, u0, G0, q1, r1, u1, G1, q2, r2, u2, G2);
        evolve_kernel_gram<<<dim3(NB * NM16), dim3(512), 0, stream>>>(
            T_pred, geo, K, G0, G1, G2, Tws, out, hk0, hk1, iks);
    } else {
        evolve_kernel_nchw<<<dim3(NB * NM16), dim3(512), 0, stream>>>(
            T_pred, geo, K, q0, q1, q2, r0, r1, r2, u0, u1, u2, Tws, out, hk0, hk1, iks);
    }
    finalize_kernel<<<dim3(NB), dim3(192), 0, stream>>>(T_pred, Tws, out, hk0, hk1);
}